// Round 1
// baseline (803.630 us; speedup 1.0000x reference)
//
#include <hip/hip_runtime.h>
#include <cmath>

#define B_    32
#define T_    96
#define N_    512
#define F_    8
#define TF_   768      // T_*F_
#define HID_  512
#define M_    16384    // B_*N_
#define KIN_  1024     // 2*HID_
#define KOUT_ 64

// workspace layout (in floats)
#define HT_OFF    ((size_t)0)
#define WPACK_OFF ((size_t)KIN_ * M_)                  // 16,777,216 floats
#define KAN_OFF   (WPACK_OFF + (size_t)KIN_ * 12 * 64) // +786,432
// total = 18,612,224 floats = ~71 MB

// ---------------------------------------------------------------------------
// Kernel B: pack spline weights:  wpack[i][kk][o]
//   kk 0..7 : spline_w[o][i][kk] * spline_scaler[o][i]
//   kk == 8 : base_w[o][i]
//   kk 9..11: 0 (padding, never read)
// ---------------------------------------------------------------------------
__global__ __launch_bounds__(256) void pack_weights_kernel(
    const float* __restrict__ base_w,
    const float* __restrict__ spline_w,
    const float* __restrict__ scaler,
    float* __restrict__ wpack)
{
    const int e = blockIdx.x * 256 + threadIdx.x;
    if (e >= KIN_ * 12 * 64) return;
    const int o  = e & 63;
    const int kk = (e >> 6) % 12;
    const int i  = e / (12 * 64);
    float v = 0.0f;
    if (kk < 8)       v = spline_w[(o * KIN_ + i) * 8 + kk] * scaler[o * KIN_ + i];
    else if (kk == 8) v = base_w[o * KIN_ + i];
    wpack[e] = v;
}

// ---------------------------------------------------------------------------
// Kernel A: ht[jOff+j][m] = tanh( sum_k Xf[m,k] * W[j,k] + bias[j] )
//   Xf[m,k] gathered from X[b][t][n][f], m=b*512+n, k=t*8+f
//   GEMM M=16384, N=512, K=768.  64x64 tile, BK=16, 4x4 micro-tile.
// ---------------------------------------------------------------------------
__global__ __launch_bounds__(256) void gemm_tanh_kernel(
    const float* __restrict__ Xs,
    const float* __restrict__ W,
    const float* __restrict__ bias,
    float* __restrict__ ht,
    int jOff)
{
    __shared__ float As[16][68];
    __shared__ float Bs[16][68];

    const int tid = threadIdx.x;
    const int tx  = tid & 15;   // m micro-dim
    const int ty  = tid >> 4;   // j micro-dim
    const int m0  = blockIdx.x * 64;
    const int j0  = blockIdx.y * 64;
    const int bb  = m0 >> 9;          // batch index (const per block; 64 | 512)
    const int n0  = m0 & 511;

    // A staging roles: one float4 per thread (fully coalesced)
    const int am = tid >> 2;           // 0..63 (row within tile)
    const int aq = tid & 3;
    const int at = aq >> 1;            // t_local 0..1
    const int af = (aq & 1) * 4;       // f4: 0 or 4
    const int an = n0 + am;

    // B staging roles: one float4 per thread
    const int bj  = tid >> 2;          // 0..63
    const int bk4 = (tid & 3) * 4;     // 0,4,8,12

    float acc[4][4] = {};

    for (int kt = 0; kt < TF_; kt += 16) {
        const int t0 = kt >> 3;
        const float4 av = *(const float4*)(Xs + bb * (T_ * N_ * F_)
                                              + (t0 + at) * (N_ * F_)
                                              + an * F_ + af);
        const float4 bv = *(const float4*)(W + (j0 + bj) * TF_ + kt + bk4);

        __syncthreads();
        {
            const int kr = at * 8 + af;
            As[kr + 0][am] = av.x;
            As[kr + 1][am] = av.y;
            As[kr + 2][am] = av.z;
            As[kr + 3][am] = av.w;
            Bs[bk4 + 0][bj] = bv.x;
            Bs[bk4 + 1][bj] = bv.y;
            Bs[bk4 + 2][bj] = bv.z;
            Bs[bk4 + 3][bj] = bv.w;
        }
        __syncthreads();

        #pragma unroll
        for (int kk = 0; kk < 16; kk++) {
            const float4 a = *(const float4*)&As[kk][tx * 4];
            const float4 b = *(const float4*)&Bs[kk][ty * 4];
            const float aarr[4] = {a.x, a.y, a.z, a.w};
            const float barr[4] = {b.x, b.y, b.z, b.w};
            #pragma unroll
            for (int p = 0; p < 4; p++)
                #pragma unroll
                for (int q = 0; q < 4; q++)
                    acc[p][q] = fmaf(aarr[p], barr[q], acc[p][q]);
        }
    }

    // epilogue: ht[(jOff+j)][m], coalesced float4 along m
    #pragma unroll
    for (int q = 0; q < 4; q++) {
        const int j = j0 + ty * 4 + q;
        const float bv = bias[j];
        float4 o4;
        o4.x = tanhf(acc[0][q] + bv);
        o4.y = tanhf(acc[1][q] + bv);
        o4.z = tanhf(acc[2][q] + bv);
        o4.w = tanhf(acc[3][q] + bv);
        *(float4*)&ht[(size_t)(jOff + j) * M_ + m0 + tx * 4] = o4;
    }
}

// ---------------------------------------------------------------------------
// Kernel C: KAN.  kan[m][o] = sum_i sum_{kk<8} bases(h[m][i])[kk]*sw[o][i][kk]
//                           + sum_i silu(h[m][i]) * base_w[o][i]
// GEMM-like: 64 rows x 64 outs per block, K chunked 8 inputs (72 K-cols) at a
// time; A (bases+silu) generated on the fly into LDS from ht.
// ---------------------------------------------------------------------------
__global__ __launch_bounds__(256) void kan_kernel(
    const float* __restrict__ ht,
    const float* __restrict__ wpack,
    float* __restrict__ kan)
{
    __shared__ float As[8 * 9 * 64];   // [il][kk(9)][row]  18 KiB
    __shared__ float Ws[8 * 12 * 64];  // [il][kk(12)][o]   24 KiB

    const int tid = threadIdx.x;
    const int tx  = tid & 15;   // o micro-dim
    const int ty  = tid >> 4;   // m micro-dim
    const int m0  = blockIdx.x * 64;
    const int row = tid & 63;
    const int il0 = tid >> 6;

    float acc[4][4] = {};

    for (int i0 = 0; i0 < KIN_; i0 += 8) {
        __syncthreads();
        // ---- stage A: bases + silu for 8 inputs x 64 rows ----
        #pragma unroll
        for (int rep = 0; rep < 2; rep++) {
            const int il = il0 + rep * 4;
            const float x = ht[(size_t)(i0 + il) * M_ + m0 + row];

            float bas[11];
            #pragma unroll
            for (int i = 0; i < 11; i++) {
                const float gi  = (float)(i - 3) * 0.4f - 1.0f;
                const float gi1 = (float)(i - 2) * 0.4f - 1.0f;
                bas[i] = (x >= gi && x < gi1) ? 1.0f : 0.0f;
            }
            #pragma unroll
            for (int k = 1; k <= 3; k++) {
                #pragma unroll
                for (int i = 0; i + k < 11; i++) {
                    const float gi   = (float)(i - 3)     * 0.4f - 1.0f;
                    const float gi1  = (float)(i - 2)     * 0.4f - 1.0f;
                    const float gik  = (float)(i + k - 3) * 0.4f - 1.0f;
                    const float gik1 = (float)(i + k - 2) * 0.4f - 1.0f;
                    const float left  = (x - gi)   * (1.0f / (gik  - gi));
                    const float right = (gik1 - x) * (1.0f / (gik1 - gi1));
                    bas[i] = left * bas[i] + right * bas[i + 1];
                }
            }
            #pragma unroll
            for (int kk = 0; kk < 8; kk++)
                As[(il * 9 + kk) * 64 + row] = bas[kk];
            const float sig = 1.0f / (1.0f + __expf(-x));
            As[(il * 9 + 8) * 64 + row] = x * sig;
        }
        // ---- stage W: bulk copy 8*12*64 floats ----
        {
            const float4* wp4 = (const float4*)(wpack + (size_t)i0 * 12 * 64);
            float4* ws4 = (float4*)Ws;
            #pragma unroll
            for (int s = 0; s < 6; s++)
                ws4[tid + 256 * s] = wp4[tid + 256 * s];
        }
        __syncthreads();

        // ---- compute: 8 inputs x 9 K-cols ----
        #pragma unroll
        for (int il = 0; il < 8; il++) {
            #pragma unroll
            for (int kk = 0; kk < 9; kk++) {
                const float4 a = *(const float4*)&As[(il * 9 + kk) * 64 + ty * 4];
                const float4 w = *(const float4*)&Ws[(il * 12 + kk) * 64 + tx * 4];
                const float aarr[4] = {a.x, a.y, a.z, a.w};
                const float warr[4] = {w.x, w.y, w.z, w.w};
                #pragma unroll
                for (int p = 0; p < 4; p++)
                    #pragma unroll
                    for (int q = 0; q < 4; q++)
                        acc[p][q] = fmaf(aarr[p], warr[q], acc[p][q]);
            }
        }
    }

    #pragma unroll
    for (int p = 0; p < 4; p++) {
        float4 o4 = make_float4(acc[p][0], acc[p][1], acc[p][2], acc[p][3]);
        *(float4*)&kan[(size_t)(m0 + ty * 4 + p) * 64 + tx * 4] = o4;
    }
}

// ---------------------------------------------------------------------------
// Kernel D: out[b][t][n][f] = sum_o kan[m][o]*Wf[tf][o] + bf[tf]
//   m = b*512+n, tf = t*8+f.  64 m x 64 tf per block, K=64 in one shot.
// ---------------------------------------------------------------------------
__global__ __launch_bounds__(256) void final_kernel(
    const float* __restrict__ kan,
    const float* __restrict__ Wf,
    const float* __restrict__ bf,
    float* __restrict__ out)
{
    __shared__ float At[64 * 68];  // [o][m]
    __shared__ float Bt[64 * 68];  // [o][tf]

    const int tid = threadIdx.x;
    const int tx  = tid & 15;   // tf micro-dim
    const int ty  = tid >> 4;   // m micro-dim
    const int m0  = blockIdx.x * 64;
    const int tf0 = blockIdx.y * 64;

    // staging roles
    const int r  = tid & 15;
    const int c4 = (tid >> 4) * 4;

    #pragma unroll
    for (int s = 0; s < 4; s++) {
        const int rw = r + s * 16;
        const float4 k4 = *(const float4*)&kan[(size_t)(m0 + rw) * 64 + c4];
        At[(c4 + 0) * 68 + rw] = k4.x;
        At[(c4 + 1) * 68 + rw] = k4.y;
        At[(c4 + 2) * 68 + rw] = k4.z;
        At[(c4 + 3) * 68 + rw] = k4.w;
        const float4 w4 = *(const float4*)&Wf[(size_t)(tf0 + rw) * 64 + c4];
        Bt[(c4 + 0) * 68 + rw] = w4.x;
        Bt[(c4 + 1) * 68 + rw] = w4.y;
        Bt[(c4 + 2) * 68 + rw] = w4.z;
        Bt[(c4 + 3) * 68 + rw] = w4.w;
    }
    __syncthreads();

    float acc[4][4] = {};
    #pragma unroll 8
    for (int o = 0; o < 64; o++) {
        const float4 a = *(const float4*)&At[o * 68 + ty * 4];
        const float4 w = *(const float4*)&Bt[o * 68 + tx * 4];
        const float aarr[4] = {a.x, a.y, a.z, a.w};
        const float warr[4] = {w.x, w.y, w.z, w.w};
        #pragma unroll
        for (int p = 0; p < 4; p++)
            #pragma unroll
            for (int q = 0; q < 4; q++)
                acc[p][q] = fmaf(aarr[p], warr[q], acc[p][q]);
    }

    // epilogue: add bias, scatter to [b][t][n][f]
    const int tf = tf0 + tx * 4;        // 4 consecutive tf, same t (f=0 or 4)
    const float4 b4 = *(const float4*)&bf[tf];
    const int t  = tf >> 3;
    const int f0 = tf & 7;
    const int bb = m0 >> 9;
    const int n0 = (m0 & 511) + ty * 4;

    #pragma unroll
    for (int p = 0; p < 4; p++) {
        float4 o4 = make_float4(acc[p][0] + b4.x, acc[p][1] + b4.y,
                                acc[p][2] + b4.z, acc[p][3] + b4.w);
        *(float4*)&out[(size_t)bb * (T_ * N_ * F_)
                       + (size_t)t * (N_ * F_)
                       + (size_t)(n0 + p) * F_ + f0] = o4;
    }
}

// ---------------------------------------------------------------------------
extern "C" void kernel_launch(void* const* d_in, const int* in_sizes, int n_in,
                              void* d_out, int out_size, void* d_ws, size_t ws_size,
                              hipStream_t stream)
{
    const float* X      = (const float*)d_in[0];
    const float* Y      = (const float*)d_in[1];
    const float* Wx     = (const float*)d_in[2];
    const float* bx     = (const float*)d_in[3];
    const float* Wy     = (const float*)d_in[4];
    const float* by     = (const float*)d_in[5];
    const float* base_w = (const float*)d_in[6];
    const float* spline_w = (const float*)d_in[7];
    const float* spline_scaler = (const float*)d_in[8];
    const float* Wf     = (const float*)d_in[9];
    const float* bf     = (const float*)d_in[10];

    float* out = (float*)d_out;
    float* ws  = (float*)d_ws;

    float* ht    = ws + HT_OFF;     // [1024][16384]
    float* wpack = ws + WPACK_OFF;  // [1024][12][64]
    float* kan   = ws + KAN_OFF;    // [16384][64]

    pack_weights_kernel<<<(KIN_ * 12 * 64) / 256, 256, 0, stream>>>(
        base_w, spline_w, spline_scaler, wpack);

    gemm_tanh_kernel<<<dim3(M_ / 64, HID_ / 64), 256, 0, stream>>>(
        X, Wx, bx, ht, 0);
    gemm_tanh_kernel<<<dim3(M_ / 64, HID_ / 64), 256, 0, stream>>>(
        Y, Wy, by, ht, HID_);

    kan_kernel<<<M_ / 64, 256, 0, stream>>>(ht, wpack, kan);

    final_kernel<<<dim3(M_ / 64, TF_ / 64), 256, 0, stream>>>(
        kan, Wf, bf, out);
}

// Round 2
// 251.766 us; speedup vs baseline: 3.1920x; 3.1920x over previous
//
#include <hip/hip_runtime.h>
#include <cmath>

#define B_    32
#define T_    96
#define N_    512
#define F_    8
#define TF_   768
#define HID_  512
#define M_    16384
#define KIN_  1024
#define KS_   4        // K-split for kan

typedef short short8 __attribute__((ext_vector_type(8)));
typedef float f32x4  __attribute__((ext_vector_type(4)));
typedef unsigned short      ushort_t;
typedef unsigned int        uint_t;
typedef unsigned long long  ulong_t;

// workspace byte offsets
#define HT_B     0ull                    // bf16 ht[1024][16384]     = 33,554,432 B
#define WPACK_B  33554432ull             // bf16 wpack[128][64][96]  =  1,572,864 B
#define KANP_B   35127296ull             // f32 kanp[4][16384][64]   = 16,777,216 B

__device__ inline ushort_t f2b(float f) {
    uint_t u = __builtin_bit_cast(uint_t, f);
    return (ushort_t)((u + 0x7fffu + ((u >> 16) & 1u)) >> 16);
}
__device__ inline float b2f(ushort_t h) {
    return __builtin_bit_cast(float, (uint_t)h << 16);
}
__device__ inline ulong_t pack4(float4 v) {
    return (ulong_t)f2b(v.x) | ((ulong_t)f2b(v.y) << 16) |
           ((ulong_t)f2b(v.z) << 32) | ((ulong_t)f2b(v.w) << 48);
}

// ---------------------------------------------------------------------------
// pack spline+base weights to bf16: wpack[gc][o][k], k = il*12 + kk, i = gc*8+il
// kk 0..7: spline_w[o][i][kk]*scaler[o][i]; kk==8: base_w[o][i]; 9..11: 0
// ---------------------------------------------------------------------------
__global__ __launch_bounds__(256) void pack_weights_kernel(
    const float* __restrict__ base_w,
    const float* __restrict__ spline_w,
    const float* __restrict__ scaler,
    ushort_t* __restrict__ wpack)
{
    const int e = blockIdx.x * 256 + threadIdx.x;   // 128*64*96 = 786432
    if (e >= 128 * 64 * 96) return;
    const int k  = e % 96;
    const int o  = (e / 96) & 63;
    const int gc = e / (96 * 64);
    const int il = k / 12, kk = k % 12;
    const int i  = gc * 8 + il;
    float v = 0.0f;
    if (kk < 8)       v = spline_w[(o * KIN_ + i) * 8 + kk] * scaler[o * KIN_ + i];
    else if (kk == 8) v = base_w[o * KIN_ + i];
    wpack[e] = f2b(v);
}

// ---------------------------------------------------------------------------
// gemm_tanh (MFMA bf16): ht[jOff+j][m] = tanh( sum_k Xf[m,k]*W[j,k] + bias[j] )
// M=16384, N=512, K=768. 64x64 tile, BK=64, 4 waves, 16x16x32 MFMA.
// LDS tiles [row][64k] bf16, byte ^= (row&7)<<4 swizzle.
// ---------------------------------------------------------------------------
__global__ __launch_bounds__(256) void gemm_tanh_mfma(
    const float* __restrict__ Xs,
    const float* __restrict__ W,
    const float* __restrict__ bias,
    ushort_t* __restrict__ ht,
    int jOff)
{
    __shared__ __align__(16) char smem[16384];
    ushort_t* As = (ushort_t*)smem;            // [64][64] bf16, swizzled
    ushort_t* Bs = (ushort_t*)(smem + 8192);   // [64][64] bf16, swizzled

    const int tid = threadIdx.x;
    const int wv  = tid >> 6;
    const int ln  = tid & 63;
    const int m0  = blockIdx.x * 64;
    const int j0  = blockIdx.y * 64;
    const int bb  = m0 >> 9;
    const int n0  = m0 & 511;

    const int arow = tid & 63;        // A staging: row, aq==wv
    const int bkg  = tid & 15;        // B staging: k-group
    const int bjl  = tid >> 4;        // 0..15

    f32x4 acc[4] = {};

    for (int kt = 0; kt < TF_; kt += 64) {
        const int t0 = kt >> 3;
        float4 av[4], bv[4];
        #pragma unroll
        for (int s = 0; s < 4; s++) {
            const int idx = wv * 4 + s;            // 0..15
            const int tl = idx >> 1, f0 = (idx & 1) * 4;
            av[s] = *(const float4*)(Xs + (size_t)bb * (T_ * N_ * F_)
                                       + (size_t)(t0 + tl) * (N_ * F_)
                                       + (size_t)(n0 + arow) * F_ + f0);
        }
        #pragma unroll
        for (int s = 0; s < 4; s++) {
            const int j = s * 16 + bjl;
            bv[s] = *(const float4*)(W + (size_t)(j0 + j) * TF_ + kt + bkg * 4);
        }
        __syncthreads();   // previous iter's MFMA reads done
        #pragma unroll
        for (int s = 0; s < 4; s++) {
            const int k0 = (wv * 4 + s) * 4;       // 4 bf16 at [arow][k0]
            *(ulong_t*)(smem + ((arow * 128 + k0 * 2) ^ ((arow & 7) << 4))) = pack4(av[s]);
        }
        #pragma unroll
        for (int s = 0; s < 4; s++) {
            const int j = s * 16 + bjl;
            *(ulong_t*)(smem + 8192 + ((j * 128 + bkg * 8) ^ ((j & 7) << 4))) = pack4(bv[s]);
        }
        __syncthreads();

        #pragma unroll
        for (int ksq = 0; ksq < 2; ksq++) {
            const int k0 = ksq * 32 + (ln >> 4) * 8;
            const int ar = wv * 16 + (ln & 15);
            short8 a = *(short8*)(smem + ((ar * 128 + k0 * 2) ^ ((ar & 7) << 4)));
            #pragma unroll
            for (int ct = 0; ct < 4; ct++) {
                const int br = ct * 16 + (ln & 15);
                short8 b = *(short8*)(smem + 8192 + ((br * 128 + k0 * 2) ^ ((br & 7) << 4)));
                acc[ct] = __builtin_amdgcn_mfma_f32_16x16x32_bf16(a, b, acc[ct], 0, 0, 0);
            }
        }
    }

    // epilogue: tanh + transpose via LDS (bf16 [j][m], mild swizzle), store ht[j][m]
    __syncthreads();
    #pragma unroll
    for (int ct = 0; ct < 4; ct++) {
        const int j = ct * 16 + (ln & 15);
        const float bvv = bias[j0 + j];
        #pragma unroll
        for (int q = 0; q < 4; q++) {
            const int m = wv * 16 + 4 * (ln >> 4) + q;
            const float v = tanhf(acc[ct][q] + bvv);
            *(ushort_t*)(smem + ((j * 128 + m * 2) ^ ((j & 3) << 5))) = f2b(v);
        }
    }
    __syncthreads();
    {
        const int j  = tid >> 2;
        const int mq = (tid & 3) * 16;
        ushort_t* dst = ht + (size_t)(jOff + j0 + j) * M_ + m0 + mq;
        *(short8*)(dst)     = *(short8*)(smem + ((j * 128 + mq * 2)      ^ ((j & 3) << 5)));
        *(short8*)(dst + 8) = *(short8*)(smem + ((j * 128 + mq * 2 + 16) ^ ((j & 3) << 5)));
    }
}

// ---------------------------------------------------------------------------
// kan (MFMA bf16): kanp[ks][m][o] = partial over inputs [ks*256, ks*256+256)
// A[row][k=il*12+kk]: closed-form cubic B-spline bases (4 nonzero) + silu.
// 64 rows x 64 outs per block; chunk = 8 inputs = 96 K-cols = 3 MFMA K-steps.
// ---------------------------------------------------------------------------
__global__ __launch_bounds__(256) void kan_mfma(
    const ushort_t* __restrict__ ht,
    const ushort_t* __restrict__ wpack,
    float* __restrict__ kanp)
{
    __shared__ __align__(16) char smem[24576];
    // As: [64 rows][96 k] bf16 (stride 192 B) ; Ws: [64 o][96 k] bf16

    const int tid = threadIdx.x;
    const int wv  = tid >> 6;
    const int ln  = tid & 63;
    const int m0  = blockIdx.x * 64;
    const int ks  = blockIdx.y;
    const int iBase = ks * (KIN_ / KS_);

    // zero pad slots 9..11 (bytes 18..23 of each 24B strip) — never rewritten
    {
        const int row = tid & 63;
        #pragma unroll
        for (int r2 = 0; r2 < 2; r2++) {
            const int il = (tid >> 6) + r2 * 4;
            char* p = smem + row * 192 + il * 24 + 18;
            *(ushort_t*)p = 0; *(ushort_t*)(p + 2) = 0; *(ushort_t*)(p + 4) = 0;
        }
    }

    f32x4 acc[4] = {};

    for (int c = 0; c < (KIN_ / KS_) / 8; c++) {
        const int i0 = iBase + c * 8;
        // load x values (2 per thread) and weight chunk (3 x 16B per thread)
        float xv[2];
        xv[0] = b2f(ht[(size_t)(i0 + (tid >> 6)) * M_ + m0 + (tid & 63)]);
        xv[1] = b2f(ht[(size_t)(i0 + (tid >> 6) + 4) * M_ + m0 + (tid & 63)]);
        const ushort_t* wp = wpack + (size_t)(i0 >> 3) * 6144;
        short8 wreg[3];
        #pragma unroll
        for (int s = 0; s < 3; s++)
            wreg[s] = *(const short8*)(wp + tid * 8 + s * 2048);

        __syncthreads();   // previous iter's MFMA reads done

        #pragma unroll
        for (int e = 0; e < 2; e++) {
            const int row = tid & 63;
            const int il  = (tid >> 6) + e * 4;
            const float x = xv[e];
            // closed-form uniform cubic B-spline: segment + 4 nonzero bases
            const float v  = (x + 1.0f) * 2.5f;
            float sf = floorf(v);
            sf = fminf(fmaxf(sf, 0.0f), 4.0f);
            const float u  = v - sf;
            const int  si  = (int)sf;
            const float omu = 1.0f - u;
            const float u2 = u * u, u3 = u2 * u;
            const float Bb0 = omu * omu * omu * (1.0f / 6.0f);
            const float Bb1 = 0.5f * u3 - u2 + (2.0f / 3.0f);
            const float Bb3 = u3 * (1.0f / 6.0f);
            const float Bb2 = 1.0f - Bb0 - Bb1 - Bb3;
            const float sil = x / (1.0f + __expf(-x));

            char* base = smem + row * 192 + il * 24;
            *(ulong_t*)base       = 0ull;      // slots 0..3
            *(ulong_t*)(base + 8) = 0ull;      // slots 4..7
            *(ushort_t*)(base + 2 * si)     = f2b(Bb0);
            *(ushort_t*)(base + 2 * si + 2) = f2b(Bb1);
            *(ushort_t*)(base + 2 * si + 4) = f2b(Bb2);
            *(ushort_t*)(base + 2 * si + 6) = f2b(Bb3);
            *(ushort_t*)(base + 16)         = f2b(sil);   // slot 8
        }
        #pragma unroll
        for (int s = 0; s < 3; s++)
            *(short8*)(smem + 12288 + tid * 16 + s * 4096) = wreg[s];

        __syncthreads();

        #pragma unroll
        for (int t3 = 0; t3 < 3; t3++) {
            const int k0 = t3 * 32 + (ln >> 4) * 8;
            const int ar = wv * 16 + (ln & 15);
            short8 a = *(short8*)(smem + ar * 192 + k0 * 2);
            #pragma unroll
            for (int ct = 0; ct < 4; ct++) {
                const int br = ct * 16 + (ln & 15);
                short8 b = *(short8*)(smem + 12288 + br * 192 + k0 * 2);
                acc[ct] = __builtin_amdgcn_mfma_f32_16x16x32_bf16(a, b, acc[ct], 0, 0, 0);
            }
        }
    }

    // epilogue: transpose via LDS f32 [64][68], coalesced f4 stores
    __syncthreads();
    float* T = (float*)smem;
    #pragma unroll
    for (int ct = 0; ct < 4; ct++)
        #pragma unroll
        for (int q = 0; q < 4; q++)
            T[(wv * 16 + 4 * (ln >> 4) + q) * 68 + ct * 16 + (ln & 15)] = acc[ct][q];
    __syncthreads();
    {
        const int m  = tid >> 2;
        const int o4 = (tid & 3) * 16;
        float* dst = kanp + ((size_t)ks * M_ + m0 + m) * 64 + o4;
        #pragma unroll
        for (int w = 0; w < 4; w++)
            *(float4*)(dst + w * 4) = *(float4*)&T[m * 68 + o4 + w * 4];
    }
}

// ---------------------------------------------------------------------------
// final: out[b][t][n][f] = sum_ks sum_o kanp[ks][m][o]*Wf[tf][o] + bf[tf]
// ---------------------------------------------------------------------------
__global__ __launch_bounds__(256) void final_kernel(
    const float* __restrict__ kanp,
    const float* __restrict__ Wf,
    const float* __restrict__ bf,
    float* __restrict__ out)
{
    __shared__ float At[64 * 68];  // [o][m]
    __shared__ float Bt[64 * 68];  // [o][tf]

    const int tid = threadIdx.x;
    const int tx  = tid & 15;
    const int ty  = tid >> 4;
    const int m0  = blockIdx.x * 64;
    const int tf0 = blockIdx.y * 64;

    const int r  = tid & 15;
    const int c4 = (tid >> 4) * 4;

    #pragma unroll
    for (int s = 0; s < 4; s++) {
        const int rw = r + s * 16;
        float4 k4 = *(const float4*)&kanp[(size_t)(m0 + rw) * 64 + c4];
        #pragma unroll
        for (int p = 1; p < KS_; p++) {
            const float4 kp = *(const float4*)&kanp[(size_t)p * M_ * 64 + (size_t)(m0 + rw) * 64 + c4];
            k4.x += kp.x; k4.y += kp.y; k4.z += kp.z; k4.w += kp.w;
        }
        At[(c4 + 0) * 68 + rw] = k4.x;
        At[(c4 + 1) * 68 + rw] = k4.y;
        At[(c4 + 2) * 68 + rw] = k4.z;
        At[(c4 + 3) * 68 + rw] = k4.w;
        const float4 w4 = *(const float4*)&Wf[(size_t)(tf0 + rw) * 64 + c4];
        Bt[(c4 + 0) * 68 + rw] = w4.x;
        Bt[(c4 + 1) * 68 + rw] = w4.y;
        Bt[(c4 + 2) * 68 + rw] = w4.z;
        Bt[(c4 + 3) * 68 + rw] = w4.w;
    }
    __syncthreads();

    float acc[4][4] = {};
    #pragma unroll 8
    for (int o = 0; o < 64; o++) {
        const float4 a = *(const float4*)&At[o * 68 + ty * 4];
        const float4 w = *(const float4*)&Bt[o * 68 + tx * 4];
        const float aarr[4] = {a.x, a.y, a.z, a.w};
        const float warr[4] = {w.x, w.y, w.z, w.w};
        #pragma unroll
        for (int p = 0; p < 4; p++)
            #pragma unroll
            for (int q = 0; q < 4; q++)
                acc[p][q] = fmaf(aarr[p], warr[q], acc[p][q]);
    }

    const int tf = tf0 + tx * 4;
    const float4 b4 = *(const float4*)&bf[tf];
    const int t  = tf >> 3;
    const int f0 = tf & 7;
    const int bb = m0 >> 9;
    const int n0 = (m0 & 511) + ty * 4;

    #pragma unroll
    for (int p = 0; p < 4; p++) {
        float4 o4 = make_float4(acc[p][0] + b4.x, acc[p][1] + b4.y,
                                acc[p][2] + b4.z, acc[p][3] + b4.w);
        *(float4*)&out[(size_t)bb * (T_ * N_ * F_)
                       + (size_t)t * (N_ * F_)
                       + (size_t)(n0 + p) * F_ + f0] = o4;
    }
}

// ---------------------------------------------------------------------------
extern "C" void kernel_launch(void* const* d_in, const int* in_sizes, int n_in,
                              void* d_out, int out_size, void* d_ws, size_t ws_size,
                              hipStream_t stream)
{
    const float* X      = (const float*)d_in[0];
    const float* Y      = (const float*)d_in[1];
    const float* Wx     = (const float*)d_in[2];
    const float* bx     = (const float*)d_in[3];
    const float* Wy     = (const float*)d_in[4];
    const float* by     = (const float*)d_in[5];
    const float* base_w = (const float*)d_in[6];
    const float* spline_w = (const float*)d_in[7];
    const float* spline_scaler = (const float*)d_in[8];
    const float* Wf     = (const float*)d_in[9];
    const float* bf     = (const float*)d_in[10];

    float* out = (float*)d_out;
    ushort_t* ht    = (ushort_t*)((char*)d_ws + HT_B);
    ushort_t* wpack = (ushort_t*)((char*)d_ws + WPACK_B);
    float*    kanp  = (float*)((char*)d_ws + KANP_B);

    pack_weights_kernel<<<3072, 256, 0, stream>>>(base_w, spline_w, spline_scaler, wpack);

    gemm_tanh_mfma<<<dim3(M_ / 64, HID_ / 64), 256, 0, stream>>>(X, Wx, bx, ht, 0);
    gemm_tanh_mfma<<<dim3(M_ / 64, HID_ / 64), 256, 0, stream>>>(Y, Wy, by, ht, HID_);

    kan_mfma<<<dim3(M_ / 64, KS_), 256, 0, stream>>>(ht, wpack, kanp);

    final_kernel<<<dim3(M_ / 64, TF_ / 64), 256, 0, stream>>>(kanp, Wf, bf, out);
}

// Round 3
// 200.420 us; speedup vs baseline: 4.0097x; 1.2562x over previous
//
#include <hip/hip_runtime.h>
#include <cmath>

#define B_    32
#define T_    96
#define N_    512
#define F_    8
#define TF_   768
#define HID_  512
#define M_    16384
#define KIN_  1024
#define KS_   8        // K-split for kan
#define RPB_  128      // rows per kan block

typedef short short8 __attribute__((ext_vector_type(8)));
typedef float f32x4  __attribute__((ext_vector_type(4)));
typedef unsigned int  uintx4 __attribute__((ext_vector_type(4)));
typedef unsigned long long ulongx2 __attribute__((ext_vector_type(2)));
typedef unsigned short      ushort_t;
typedef unsigned int        uint_t;
typedef unsigned long long  ulong_t;

// workspace byte offsets
#define HT_B    0ull                 // bf16 ht[1024][16384]            = 33,554,432 B
#define WQ_B    33554432ull          // bf16 wq[8][9][4][4][64][8]      =  1,179,648 B
#define KANP_B  34734080ull          // f32 kanp[8][16384][64]          = 33,554,432 B

static __device__ inline uint_t  fbits(float f){ return __builtin_bit_cast(uint_t, f); }
static __device__ inline ushort_t f2b(float f){
    uint_t u = fbits(f);
    return (ushort_t)((u + 0x7fffu + ((u >> 16) & 1u)) >> 16);
}
static __device__ inline float b2f(ushort_t h){ return __builtin_bit_cast(float, (uint_t)h << 16); }
static __device__ inline ulong_t pack4(float4 v){
    return (ulong_t)f2b(v.x) | ((ulong_t)f2b(v.y) << 16) |
           ((ulong_t)f2b(v.z) << 32) | ((ulong_t)f2b(v.w) << 48);
}
static __device__ inline float fast_tanh(float x){
    const float e = __expf(2.0f * x);
    return 1.0f - 2.0f / (e + 1.0f);
}

// ---------------------------------------------------------------------------
// pack_wq: weights in exact MFMA B-fragment order.
// wq[ks][ss][t][ct][ln][j], bf16.  o = ct*16 + (ln&15), g = ln>>4.
//   ss<8 (bases K-steps): i = ks*128 + ss*16 + t*4 + g, val = spline_w[o][i][j]*scaler[o][i]
//   ss==8 (silu K-steps): i = ks*128 + t*32 + g*8 + j,  val = base_w[o][i]
// ---------------------------------------------------------------------------
__global__ __launch_bounds__(256) void pack_wq(
    const float* __restrict__ base_w,
    const float* __restrict__ spline_w,
    const float* __restrict__ scaler,
    ushort_t* __restrict__ wq)
{
    const int e = blockIdx.x * 256 + threadIdx.x;   // 8*9*4*4*64*8 = 589824
    const int j    = e & 7;
    const int ln   = (e >> 3) & 63;
    const int ct   = (e >> 9) & 3;
    const int t    = (e >> 11) & 3;
    const int rest = e >> 13;        // 0..71
    const int ss   = rest % 9;
    const int ks   = rest / 9;
    const int o = ct * 16 + (ln & 15);
    const int g = ln >> 4;
    float v;
    if (ss < 8) {
        const int i = ks * 128 + ss * 16 + t * 4 + g;
        v = spline_w[(o * KIN_ + i) * 8 + j] * scaler[o * KIN_ + i];
    } else {
        const int i = ks * 128 + t * 32 + g * 8 + j;
        v = base_w[o * KIN_ + i];
    }
    wq[e] = f2b(v);
}

// ---------------------------------------------------------------------------
// gemm_tanh (MFMA bf16): ht[jOff+j][m] = tanh( sum_k Xf[m,k]*W[j,k] + bias[j] )
// blockIdx.z selects the X or Y problem.  64x64 tile, BK=64, 4 waves.
// ---------------------------------------------------------------------------
__global__ __launch_bounds__(256) void gemm_tanh_mfma(
    const float* __restrict__ X, const float* __restrict__ Y,
    const float* __restrict__ Wx, const float* __restrict__ Wy,
    const float* __restrict__ bx, const float* __restrict__ by,
    ushort_t* __restrict__ ht)
{
    __shared__ __align__(16) char smem[16384];

    const int z = blockIdx.z;
    const float* Xs   = z ? Y  : X;
    const float* W    = z ? Wy : Wx;
    const float* bias = z ? by : bx;
    const int jOff    = z ? HID_ : 0;

    const int tid = threadIdx.x;
    const int wv  = tid >> 6;
    const int ln  = tid & 63;
    const int m0  = blockIdx.x * 64;
    const int j0  = blockIdx.y * 64;
    const int bb  = m0 >> 9;
    const int n0  = m0 & 511;

    const int arow = tid & 63;        // A staging: row; this thread covers k = wv*16..+16
    const int bkg  = tid & 15;        // B staging: k-group
    const int bjl  = tid >> 4;        // 0..15

    f32x4 acc[4] = {};

    for (int kt = 0; kt < TF_; kt += 64) {
        const int t0 = kt >> 3;
        float4 av[4], bv[4];
        #pragma unroll
        for (int s = 0; s < 4; s++) {
            const int idx = wv * 4 + s;            // k-local = idx*4
            const int tl = idx >> 1, f0 = (idx & 1) * 4;
            av[s] = *(const float4*)(Xs + (size_t)bb * (T_ * N_ * F_)
                                       + (size_t)(t0 + tl) * (N_ * F_)
                                       + (size_t)(n0 + arow) * F_ + f0);
        }
        #pragma unroll
        for (int s = 0; s < 4; s++) {
            const int j = s * 16 + bjl;
            bv[s] = *(const float4*)(W + (size_t)(j0 + j) * TF_ + kt + bkg * 4);
        }
        __syncthreads();
        {
            // A: 16 consecutive k per thread -> 2x b128 swizzled writes
            uint_t d[8];
            #pragma unroll
            for (int s = 0; s < 4; s++) {
                d[2*s]   = (uint_t)f2b(av[s].x) | ((uint_t)f2b(av[s].y) << 16);
                d[2*s+1] = (uint_t)f2b(av[s].z) | ((uint_t)f2b(av[s].w) << 16);
            }
            uintx4 lo4 = {d[0], d[1], d[2], d[3]};
            uintx4 hi4 = {d[4], d[5], d[6], d[7]};
            const int abase = arow * 128 + wv * 32;
            *(uintx4*)(smem + ((abase)      ^ ((arow & 7) << 4))) = lo4;
            *(uintx4*)(smem + ((abase + 16) ^ ((arow & 7) << 4))) = hi4;
        }
        #pragma unroll
        for (int s = 0; s < 4; s++) {
            const int j = s * 16 + bjl;
            *(ulong_t*)(smem + 8192 + ((j * 128 + bkg * 8) ^ ((j & 7) << 4))) = pack4(bv[s]);
        }
        __syncthreads();

        #pragma unroll
        for (int ksq = 0; ksq < 2; ksq++) {
            const int k0 = ksq * 32 + (ln >> 4) * 8;
            const int ar = wv * 16 + (ln & 15);
            short8 a = *(short8*)(smem + ((ar * 128 + k0 * 2) ^ ((ar & 7) << 4)));
            #pragma unroll
            for (int ct = 0; ct < 4; ct++) {
                const int br = ct * 16 + (ln & 15);
                short8 b = *(short8*)(smem + 8192 + ((br * 128 + k0 * 2) ^ ((br & 7) << 4)));
                acc[ct] = __builtin_amdgcn_mfma_f32_16x16x32_bf16(a, b, acc[ct], 0, 0, 0);
            }
        }
    }

    // epilogue: tanh + transpose via LDS (bf16 [j][m]), store ht[j][m]
    __syncthreads();
    #pragma unroll
    for (int ct = 0; ct < 4; ct++) {
        const int j = ct * 16 + (ln & 15);
        const float bvv = bias[j0 + j];
        #pragma unroll
        for (int q = 0; q < 4; q++) {
            const int m = wv * 16 + 4 * (ln >> 4) + q;
            const float v = fast_tanh(acc[ct][q] + bvv);
            *(ushort_t*)(smem + ((j * 128 + m * 2) ^ ((j & 3) << 5))) = f2b(v);
        }
    }
    __syncthreads();
    {
        const int j  = tid >> 2;
        const int mq = (tid & 3) * 16;
        ushort_t* dst = ht + (size_t)(jOff + j0 + j) * M_ + m0 + mq;
        *(short8*)(dst)     = *(short8*)(smem + ((j * 128 + mq * 2)      ^ ((j & 3) << 5)));
        *(short8*)(dst + 8) = *(short8*)(smem + ((j * 128 + mq * 2 + 16) ^ ((j & 3) << 5)));
    }
}

// ---------------------------------------------------------------------------
// kan_v3: zero-LDS.  A-fragments built in registers (closed-form uniform cubic
// B-spline, funnel-shift scatter); B-fragments streamed from wq in frag order.
// Each wave: 32 rows (2 row-tiles) x 64 outs; block = 128 rows; grid (128, 8).
// ---------------------------------------------------------------------------
static __device__ inline short8 eval_bases(float x)
{
    const float v = fmaf(x, 2.5f, 2.5f);
    float sf = floorf(v);
    sf = fminf(fmaxf(sf, 0.0f), 4.0f);
    const float u = v - sf;
    const int si = (int)sf;
    const float u2 = u * u, u3 = u2 * u;
    const float omu = 1.0f - u;
    const float omu3 = omu * omu * omu;
    const float Bb0 = omu3 * (1.0f / 6.0f);
    const float Bb3 = u3 * (1.0f / 6.0f);
    const float Bb1 = fmaf(0.5f, u3, 2.0f / 3.0f) - u2;
    const float Bb2 = 1.0f - Bb0 - Bb1 - Bb3;
    // truncation-pack to bf16 (headroom in threshold; saves ~10 VALU/eval)
    const uint_t d0 = (fbits(Bb0) >> 16) | (fbits(Bb1) & 0xffff0000u);
    const uint_t d1 = (fbits(Bb2) >> 16) | (fbits(Bb3) & 0xffff0000u);
    const ulong_t P = (ulong_t)d0 | ((ulong_t)d1 << 32);
    const int sh = si << 4;
    const ulong_t Plo = P << (sh & 63);
    const ulong_t Phi = P >> ((64 - sh) & 63);
    ulongx2 pr;
    pr.x = (si == 4) ? 0ull : Plo;
    pr.y = (si == 0) ? 0ull : ((si == 4) ? P : Phi);
    return __builtin_bit_cast(short8, pr);
}

static __device__ inline short8 eval_silu8(const ushort_t* __restrict__ ht, int ib0, size_t r)
{
    uintx4 d;
    #pragma unroll
    for (int jj = 0; jj < 4; jj++) {
        const float x0 = b2f(ht[(size_t)(ib0 + 2 * jj)     * M_ + r]);
        const float x1 = b2f(ht[(size_t)(ib0 + 2 * jj + 1) * M_ + r]);
        const float s0 = x0 / (1.0f + __expf(-x0));
        const float s1 = x1 / (1.0f + __expf(-x1));
        d[jj] = (fbits(s0) >> 16) | (fbits(s1) & 0xffff0000u);
    }
    return __builtin_bit_cast(short8, d);
}

__global__ __launch_bounds__(256) void kan_v3(
    const ushort_t* __restrict__ ht,
    const ushort_t* __restrict__ wq,
    float* __restrict__ kanp)
{
    const int tid = threadIdx.x;
    const int wv  = tid >> 6;
    const int ln  = tid & 63;
    const int g   = ln >> 4;
    const int lr  = ln & 15;
    const int m0  = blockIdx.x * RPB_;
    const int ks  = blockIdx.y;
    const int iB  = ks * (KIN_ / KS_);
    const size_t r0 = (size_t)(m0 + wv * 32 + lr);
    const size_t r1 = r0 + 16;

    const short8* wqf = (const short8*)wq + (size_t)ks * 9216 + ln;

    f32x4 acc[2][4] = {};

    for (int ss = 0; ss < 8; ss++) {
        #pragma unroll
        for (int t = 0; t < 4; t++) {
            const short8* bp = wqf + (size_t)(ss * 4 + t) * 256;
            const short8 b0 = bp[0], b1 = bp[64], b2 = bp[128], b3 = bp[192];
            const int i = iB + ss * 16 + t * 4 + g;
            const short8 a0 = eval_bases(b2f(ht[(size_t)i * M_ + r0]));
            const short8 a1 = eval_bases(b2f(ht[(size_t)i * M_ + r1]));
            acc[0][0] = __builtin_amdgcn_mfma_f32_16x16x32_bf16(a0, b0, acc[0][0], 0, 0, 0);
            acc[0][1] = __builtin_amdgcn_mfma_f32_16x16x32_bf16(a0, b1, acc[0][1], 0, 0, 0);
            acc[0][2] = __builtin_amdgcn_mfma_f32_16x16x32_bf16(a0, b2, acc[0][2], 0, 0, 0);
            acc[0][3] = __builtin_amdgcn_mfma_f32_16x16x32_bf16(a0, b3, acc[0][3], 0, 0, 0);
            acc[1][0] = __builtin_amdgcn_mfma_f32_16x16x32_bf16(a1, b0, acc[1][0], 0, 0, 0);
            acc[1][1] = __builtin_amdgcn_mfma_f32_16x16x32_bf16(a1, b1, acc[1][1], 0, 0, 0);
            acc[1][2] = __builtin_amdgcn_mfma_f32_16x16x32_bf16(a1, b2, acc[1][2], 0, 0, 0);
            acc[1][3] = __builtin_amdgcn_mfma_f32_16x16x32_bf16(a1, b3, acc[1][3], 0, 0, 0);
        }
    }
    // silu superstep (ss == 8)
    #pragma unroll
    for (int t = 0; t < 4; t++) {
        const short8* bp = wqf + (size_t)(32 + t) * 256;
        const short8 b0 = bp[0], b1 = bp[64], b2 = bp[128], b3 = bp[192];
        const int ib0 = iB + t * 32 + g * 8;
        const short8 a0 = eval_silu8(ht, ib0, r0);
        const short8 a1 = eval_silu8(ht, ib0, r1);
        acc[0][0] = __builtin_amdgcn_mfma_f32_16x16x32_bf16(a0, b0, acc[0][0], 0, 0, 0);
        acc[0][1] = __builtin_amdgcn_mfma_f32_16x16x32_bf16(a0, b1, acc[0][1], 0, 0, 0);
        acc[0][2] = __builtin_amdgcn_mfma_f32_16x16x32_bf16(a0, b2, acc[0][2], 0, 0, 0);
        acc[0][3] = __builtin_amdgcn_mfma_f32_16x16x32_bf16(a0, b3, acc[0][3], 0, 0, 0);
        acc[1][0] = __builtin_amdgcn_mfma_f32_16x16x32_bf16(a1, b0, acc[1][0], 0, 0, 0);
        acc[1][1] = __builtin_amdgcn_mfma_f32_16x16x32_bf16(a1, b1, acc[1][1], 0, 0, 0);
        acc[1][2] = __builtin_amdgcn_mfma_f32_16x16x32_bf16(a1, b2, acc[1][2], 0, 0, 0);
        acc[1][3] = __builtin_amdgcn_mfma_f32_16x16x32_bf16(a1, b3, acc[1][3], 0, 0, 0);
    }

    // epilogue: C layout col = ln&15, row = (ln>>4)*4 + q
    const int orow = (ln >> 4) * 4;
    #pragma unroll
    for (int rt = 0; rt < 2; rt++) {
        #pragma unroll
        for (int ct = 0; ct < 4; ct++) {
            const int o = ct * 16 + lr;
            #pragma unroll
            for (int q = 0; q < 4; q++) {
                const size_t row = (size_t)(m0 + wv * 32 + rt * 16 + orow + q);
                kanp[((size_t)ks * M_ + row) * 64 + o] = acc[rt][ct][q];
            }
        }
    }
}

// ---------------------------------------------------------------------------
// final: out[b][t][n][f] = sum_ks sum_o kanp[ks][m][o]*Wf[tf][o] + bf[tf]
// ---------------------------------------------------------------------------
__global__ __launch_bounds__(256) void final_kernel(
    const float* __restrict__ kanp,
    const float* __restrict__ Wf,
    const float* __restrict__ bf,
    float* __restrict__ out)
{
    __shared__ float At[64 * 68];  // [o][m]
    __shared__ float Bt[64 * 68];  // [o][tf]

    const int tid = threadIdx.x;
    const int tx  = tid & 15;
    const int ty  = tid >> 4;
    const int m0  = blockIdx.x * 64;
    const int tf0 = blockIdx.y * 64;

    const int r  = tid & 15;
    const int c4 = (tid >> 4) * 4;

    #pragma unroll
    for (int s = 0; s < 4; s++) {
        const int rw = r + s * 16;
        float4 k4 = *(const float4*)&kanp[(size_t)(m0 + rw) * 64 + c4];
        #pragma unroll
        for (int p = 1; p < KS_; p++) {
            const float4 kp = *(const float4*)&kanp[(size_t)p * M_ * 64 + (size_t)(m0 + rw) * 64 + c4];
            k4.x += kp.x; k4.y += kp.y; k4.z += kp.z; k4.w += kp.w;
        }
        At[(c4 + 0) * 68 + rw] = k4.x;
        At[(c4 + 1) * 68 + rw] = k4.y;
        At[(c4 + 2) * 68 + rw] = k4.z;
        At[(c4 + 3) * 68 + rw] = k4.w;
        const float4 w4 = *(const float4*)&Wf[(size_t)(tf0 + rw) * 64 + c4];
        Bt[(c4 + 0) * 68 + rw] = w4.x;
        Bt[(c4 + 1) * 68 + rw] = w4.y;
        Bt[(c4 + 2) * 68 + rw] = w4.z;
        Bt[(c4 + 3) * 68 + rw] = w4.w;
    }
    __syncthreads();

    float acc[4][4] = {};
    #pragma unroll 8
    for (int o = 0; o < 64; o++) {
        const float4 a = *(const float4*)&At[o * 68 + ty * 4];
        const float4 w = *(const float4*)&Bt[o * 68 + tx * 4];
        const float aarr[4] = {a.x, a.y, a.z, a.w};
        const float warr[4] = {w.x, w.y, w.z, w.w};
        #pragma unroll
        for (int p = 0; p < 4; p++)
            #pragma unroll
            for (int q = 0; q < 4; q++)
                acc[p][q] = fmaf(aarr[p], warr[q], acc[p][q]);
    }

    const int tf = tf0 + tx * 4;
    const float4 b4 = *(const float4*)&bf[tf];
    const int t  = tf >> 3;
    const int f0 = tf & 7;
    const int bb = m0 >> 9;
    const int n0 = (m0 & 511) + ty * 4;

    #pragma unroll
    for (int p = 0; p < 4; p++) {
        float4 o4 = make_float4(acc[p][0] + b4.x, acc[p][1] + b4.y,
                                acc[p][2] + b4.z, acc[p][3] + b4.w);
        *(float4*)&out[(size_t)bb * (T_ * N_ * F_)
                       + (size_t)t * (N_ * F_)
                       + (size_t)(n0 + p) * F_ + f0] = o4;
    }
}

// ---------------------------------------------------------------------------
extern "C" void kernel_launch(void* const* d_in, const int* in_sizes, int n_in,
                              void* d_out, int out_size, void* d_ws, size_t ws_size,
                              hipStream_t stream)
{
    const float* X      = (const float*)d_in[0];
    const float* Y      = (const float*)d_in[1];
    const float* Wx     = (const float*)d_in[2];
    const float* bx     = (const float*)d_in[3];
    const float* Wy     = (const float*)d_in[4];
    const float* by     = (const float*)d_in[5];
    const float* base_w = (const float*)d_in[6];
    const float* spline_w = (const float*)d_in[7];
    const float* spline_scaler = (const float*)d_in[8];
    const float* Wf     = (const float*)d_in[9];
    const float* bf     = (const float*)d_in[10];

    float* out = (float*)d_out;
    ushort_t* ht   = (ushort_t*)((char*)d_ws + HT_B);
    ushort_t* wq   = (ushort_t*)((char*)d_ws + WQ_B);
    float*    kanp = (float*)((char*)d_ws + KANP_B);

    pack_wq<<<2304, 256, 0, stream>>>(base_w, spline_w, spline_scaler, wq);

    gemm_tanh_mfma<<<dim3(M_ / 64, HID_ / 64, 2), 256, 0, stream>>>(
        X, Y, Wx, Wy, bx, by, ht);

    kan_v3<<<dim3(M_ / RPB_, KS_), 256, 0, stream>>>(ht, wq, kanp);

    final_kernel<<<dim3(M_ / 64, TF_ / 64), 256, 0, stream>>>(kanp, Wf, bf, out);
}

// Round 4
// 198.786 us; speedup vs baseline: 4.0427x; 1.0082x over previous
//
#include <hip/hip_runtime.h>
#include <cmath>

#define B_    32
#define T_    96
#define N_    512
#define F_    8
#define TF_   768
#define HID_  512
#define M_    16384
#define KIN_  1024
#define KS_   8        // K-split for kan
#define RPB_  128      // rows per kan block

typedef short short8 __attribute__((ext_vector_type(8)));
typedef float f32x4  __attribute__((ext_vector_type(4)));
typedef unsigned int  uintx4 __attribute__((ext_vector_type(4)));
typedef unsigned long long ulongx2 __attribute__((ext_vector_type(2)));
typedef unsigned short      ushort_t;
typedef unsigned int        uint_t;
typedef unsigned long long  ulong_t;

// workspace byte offsets
#define HT_B     0ull                // bf16 ht[1024][16384]            = 33,554,432 B
#define WQ_B     33554432ull         // bf16 wq[8][9][4][4][64][8]      =  1,179,648 B
#define WFRAG_B  34734080ull         // bf16 wfrag[2][24][32][64][8]    =  1,572,864 B
#define KANP_B   36306944ull         // f32 kanp[8][16384][64]          = 33,554,432 B

static __device__ inline uint_t  fbits(float f){ return __builtin_bit_cast(uint_t, f); }
static __device__ inline ushort_t f2b(float f){
    uint_t u = fbits(f);
    return (ushort_t)((u + 0x7fffu + ((u >> 16) & 1u)) >> 16);
}
static __device__ inline float b2f(ushort_t h){ return __builtin_bit_cast(float, (uint_t)h << 16); }
static __device__ inline ulong_t pack4(float4 v){
    return (ulong_t)f2b(v.x) | ((ulong_t)f2b(v.y) << 16) |
           ((ulong_t)f2b(v.z) << 32) | ((ulong_t)f2b(v.w) << 48);
}
static __device__ inline float fast_tanh(float x){
    const float e = __expf(2.0f * x);
    return 1.0f - 2.0f / (e + 1.0f);
}

// ---------------------------------------------------------------------------
// pack_wq: KAN weights in MFMA B-fragment order (unchanged from round 3).
// ---------------------------------------------------------------------------
__global__ __launch_bounds__(256) void pack_wq(
    const float* __restrict__ base_w,
    const float* __restrict__ spline_w,
    const float* __restrict__ scaler,
    ushort_t* __restrict__ wq)
{
    const int e = blockIdx.x * 256 + threadIdx.x;   // 589824
    const int j    = e & 7;
    const int ln   = (e >> 3) & 63;
    const int ct   = (e >> 9) & 3;
    const int t    = (e >> 11) & 3;
    const int rest = e >> 13;        // 0..71
    const int ss   = rest % 9;
    const int ks   = rest / 9;
    const int o = ct * 16 + (ln & 15);
    const int g = ln >> 4;
    float v;
    if (ss < 8) {
        const int i = ks * 128 + ss * 16 + t * 4 + g;
        v = spline_w[(o * KIN_ + i) * 8 + j] * scaler[o * KIN_ + i];
    } else {
        const int i = ks * 128 + t * 32 + g * 8 + j;
        v = base_w[o * KIN_ + i];
    }
    wq[e] = f2b(v);
}

// ---------------------------------------------------------------------------
// pack_wb: Wx/Wy bf16 in MFMA B-fragment order for gemm_tanh_v4.
// wfrag[z][ks(24)][ctg(32)][ln(64)][8]:  j = ctg*16+(ln&15), k = ks*32+(ln>>4)*8+jj
// ---------------------------------------------------------------------------
__global__ __launch_bounds__(256) void pack_wb(
    const float* __restrict__ Wx,
    const float* __restrict__ Wy,
    ushort_t* __restrict__ wfrag)
{
    const int e = blockIdx.x * 256 + threadIdx.x;   // 2*24*32*64*8 = 786432
    const int jj  = e & 7;
    const int ln  = (e >> 3) & 63;
    const int ctg = (e >> 9) & 31;
    const int rest = e >> 14;        // 0..47
    const int ks  = rest % 24;
    const int z   = rest / 24;
    const int j = ctg * 16 + (ln & 15);
    const int k = ks * 32 + (ln >> 4) * 8 + jj;
    const float* W = z ? Wy : Wx;
    wfrag[e] = f2b(W[(size_t)j * TF_ + k]);
}

// ---------------------------------------------------------------------------
// gemm_tanh_v4: ht[jOff+j][m] = tanh( sum_k Xf[m,k]*W[j,k] + bias[j] )
// BM=64, BN=512 (full N), BK=64, 512 threads (8 waves, wave = 32 rows x 128 cols).
// X gathered once per block -> LDS (8KB double-buffered, XOR-swizzled);
// B-fragments streamed directly from L2-resident wfrag. One barrier per K-step.
// ---------------------------------------------------------------------------
__global__ __launch_bounds__(512, 2) void gemm_tanh_v4(
    const float* __restrict__ X, const float* __restrict__ Y,
    const ushort_t* __restrict__ wfrag,
    const float* __restrict__ bx, const float* __restrict__ by,
    ushort_t* __restrict__ ht)
{
    __shared__ __align__(16) char smem[65536];

    const int z = blockIdx.y;
    const float* Xs   = z ? Y  : X;
    const float* bias = z ? by : bx;
    const int jOff    = z ? HID_ : 0;
    const short8* wf  = (const short8*)wfrag + (size_t)z * 24 * 32 * 64;

    const int tid = threadIdx.x;
    const int wv  = tid >> 6;
    const int ln  = tid & 63;
    const int wr  = wv >> 2;         // 0..1  (row group: 32 rows)
    const int wc  = wv & 3;          // 0..3  (col group: 128 cols)
    const int lr  = ln & 15;
    const int hi  = ln >> 4;

    const int m0  = blockIdx.x * 64;
    const int bb  = m0 >> 9;
    const int n0  = m0 & 511;

    // A staging map: row = tid>>3 (0..63), c = tid&7 (16B chunk within 128B row)
    const int srow = tid >> 3;
    const int sc   = tid & 7;
    const float* sbase = Xs + (size_t)bb * (T_ * N_ * F_) + (size_t)(n0 + srow) * F_ + sc * (size_t)(N_ * F_);

    f32x4 acc[2][8] = {};

    float4 pv0 = *(const float4*)(sbase);
    float4 pv1 = *(const float4*)(sbase + 4);

    int p = 0;
    for (int kt = 0; kt < 12; kt++) {
        // pack + write current staged regs into buf p
        ulongx2 wrt;
        wrt.x = pack4(pv0);
        wrt.y = pack4(pv1);
        *(ulongx2*)(smem + p * 8192 + ((srow * 128 + sc * 16) ^ ((srow & 7) << 4))) = wrt;
        __syncthreads();

        if (kt < 11) {
            const float* nb = sbase + (size_t)(kt + 1) * 8 * (N_ * F_);
            pv0 = *(const float4*)(nb);
            pv1 = *(const float4*)(nb + 4);
        }

        #pragma unroll
        for (int h = 0; h < 2; h++) {
            const int kb = (h * 32 + hi * 8) * 2;
            short8 a0, a1;
            {
                const int r0 = wr * 32 + lr;
                a0 = *(short8*)(smem + p * 8192 + ((r0 * 128 + kb) ^ ((lr & 7) << 4)));
                const int r1 = r0 + 16;
                a1 = *(short8*)(smem + p * 8192 + ((r1 * 128 + kb) ^ ((lr & 7) << 4)));
            }
            const int ks32 = kt * 2 + h;
            const short8* bp = wf + (size_t)(ks32 * 32 + wc * 8) * 64 + ln;
            #pragma unroll
            for (int ct = 0; ct < 8; ct++) {
                const short8 b = bp[ct * 64];
                acc[0][ct] = __builtin_amdgcn_mfma_f32_16x16x32_bf16(a0, b, acc[0][ct], 0, 0, 0);
                acc[1][ct] = __builtin_amdgcn_mfma_f32_16x16x32_bf16(a1, b, acc[1][ct], 0, 0, 0);
            }
        }
        p ^= 1;
    }

    // epilogue: bias + tanh -> LDS bf16 [j 512][m 64] (swizzled) -> coalesced ht
    __syncthreads();
    #pragma unroll
    for (int ct = 0; ct < 8; ct++) {
        const int j = wc * 128 + ct * 16 + lr;
        const float bvv = bias[j];
        #pragma unroll
        for (int ar = 0; ar < 2; ar++) {
            const f32x4 v = acc[ar][ct];
            float4 tv;
            tv.x = fast_tanh(v[0] + bvv);
            tv.y = fast_tanh(v[1] + bvv);
            tv.z = fast_tanh(v[2] + bvv);
            tv.w = fast_tanh(v[3] + bvv);
            const int m_loc = wr * 32 + ar * 16 + hi * 4;
            *(ulong_t*)(smem + ((j * 128 + m_loc * 2) ^ ((j & 7) << 4))) = pack4(tv);
        }
    }
    __syncthreads();
    #pragma unroll
    for (int pass = 0; pass < 8; pass++) {
        const int jj = pass * 64 + (tid >> 3);
        const int c  = tid & 7;
        short8 val = *(short8*)(smem + ((jj * 128 + c * 16) ^ ((jj & 7) << 4)));
        *(short8*)(ht + (size_t)(jOff + jj) * M_ + m0 + c * 8) = val;
    }
}

// ---------------------------------------------------------------------------
// kan_v3: zero-LDS (unchanged from round 3).
// ---------------------------------------------------------------------------
static __device__ inline short8 eval_bases(float x)
{
    const float v = fmaf(x, 2.5f, 2.5f);
    float sf = floorf(v);
    sf = fminf(fmaxf(sf, 0.0f), 4.0f);
    const float u = v - sf;
    const int si = (int)sf;
    const float u2 = u * u, u3 = u2 * u;
    const float omu = 1.0f - u;
    const float omu3 = omu * omu * omu;
    const float Bb0 = omu3 * (1.0f / 6.0f);
    const float Bb3 = u3 * (1.0f / 6.0f);
    const float Bb1 = fmaf(0.5f, u3, 2.0f / 3.0f) - u2;
    const float Bb2 = 1.0f - Bb0 - Bb1 - Bb3;
    const uint_t d0 = (fbits(Bb0) >> 16) | (fbits(Bb1) & 0xffff0000u);
    const uint_t d1 = (fbits(Bb2) >> 16) | (fbits(Bb3) & 0xffff0000u);
    const ulong_t P = (ulong_t)d0 | ((ulong_t)d1 << 32);
    const int sh = si << 4;
    const ulong_t Plo = P << (sh & 63);
    const ulong_t Phi = P >> ((64 - sh) & 63);
    ulongx2 pr;
    pr.x = (si == 4) ? 0ull : Plo;
    pr.y = (si == 0) ? 0ull : ((si == 4) ? P : Phi);
    return __builtin_bit_cast(short8, pr);
}

static __device__ inline short8 eval_silu8(const ushort_t* __restrict__ ht, int ib0, size_t r)
{
    uintx4 d;
    #pragma unroll
    for (int jj = 0; jj < 4; jj++) {
        const float x0 = b2f(ht[(size_t)(ib0 + 2 * jj)     * M_ + r]);
        const float x1 = b2f(ht[(size_t)(ib0 + 2 * jj + 1) * M_ + r]);
        const float s0 = x0 / (1.0f + __expf(-x0));
        const float s1 = x1 / (1.0f + __expf(-x1));
        d[jj] = (fbits(s0) >> 16) | (fbits(s1) & 0xffff0000u);
    }
    return __builtin_bit_cast(short8, d);
}

__global__ __launch_bounds__(256) void kan_v3(
    const ushort_t* __restrict__ ht,
    const ushort_t* __restrict__ wq,
    float* __restrict__ kanp)
{
    const int tid = threadIdx.x;
    const int wv  = tid >> 6;
    const int ln  = tid & 63;
    const int g   = ln >> 4;
    const int lr  = ln & 15;
    const int m0  = blockIdx.x * RPB_;
    const int ks  = blockIdx.y;
    const int iB  = ks * (KIN_ / KS_);
    const size_t r0 = (size_t)(m0 + wv * 32 + lr);
    const size_t r1 = r0 + 16;

    const short8* wqf = (const short8*)wq + (size_t)ks * 9216 + ln;

    f32x4 acc[2][4] = {};

    for (int ss = 0; ss < 8; ss++) {
        #pragma unroll
        for (int t = 0; t < 4; t++) {
            const short8* bp = wqf + (size_t)(ss * 4 + t) * 256;
            const short8 b0 = bp[0], b1 = bp[64], b2 = bp[128], b3 = bp[192];
            const int i = iB + ss * 16 + t * 4 + g;
            const short8 a0 = eval_bases(b2f(ht[(size_t)i * M_ + r0]));
            const short8 a1 = eval_bases(b2f(ht[(size_t)i * M_ + r1]));
            acc[0][0] = __builtin_amdgcn_mfma_f32_16x16x32_bf16(a0, b0, acc[0][0], 0, 0, 0);
            acc[0][1] = __builtin_amdgcn_mfma_f32_16x16x32_bf16(a0, b1, acc[0][1], 0, 0, 0);
            acc[0][2] = __builtin_amdgcn_mfma_f32_16x16x32_bf16(a0, b2, acc[0][2], 0, 0, 0);
            acc[0][3] = __builtin_amdgcn_mfma_f32_16x16x32_bf16(a0, b3, acc[0][3], 0, 0, 0);
            acc[1][0] = __builtin_amdgcn_mfma_f32_16x16x32_bf16(a1, b0, acc[1][0], 0, 0, 0);
            acc[1][1] = __builtin_amdgcn_mfma_f32_16x16x32_bf16(a1, b1, acc[1][1], 0, 0, 0);
            acc[1][2] = __builtin_amdgcn_mfma_f32_16x16x32_bf16(a1, b2, acc[1][2], 0, 0, 0);
            acc[1][3] = __builtin_amdgcn_mfma_f32_16x16x32_bf16(a1, b3, acc[1][3], 0, 0, 0);
        }
    }
    #pragma unroll
    for (int t = 0; t < 4; t++) {
        const short8* bp = wqf + (size_t)(32 + t) * 256;
        const short8 b0 = bp[0], b1 = bp[64], b2 = bp[128], b3 = bp[192];
        const int ib0 = iB + t * 32 + g * 8;
        const short8 a0 = eval_silu8(ht, ib0, r0);
        const short8 a1 = eval_silu8(ht, ib0, r1);
        acc[0][0] = __builtin_amdgcn_mfma_f32_16x16x32_bf16(a0, b0, acc[0][0], 0, 0, 0);
        acc[0][1] = __builtin_amdgcn_mfma_f32_16x16x32_bf16(a0, b1, acc[0][1], 0, 0, 0);
        acc[0][2] = __builtin_amdgcn_mfma_f32_16x16x32_bf16(a0, b2, acc[0][2], 0, 0, 0);
        acc[0][3] = __builtin_amdgcn_mfma_f32_16x16x32_bf16(a0, b3, acc[0][3], 0, 0, 0);
        acc[1][0] = __builtin_amdgcn_mfma_f32_16x16x32_bf16(a1, b0, acc[1][0], 0, 0, 0);
        acc[1][1] = __builtin_amdgcn_mfma_f32_16x16x32_bf16(a1, b1, acc[1][1], 0, 0, 0);
        acc[1][2] = __builtin_amdgcn_mfma_f32_16x16x32_bf16(a1, b2, acc[1][2], 0, 0, 0);
        acc[1][3] = __builtin_amdgcn_mfma_f32_16x16x32_bf16(a1, b3, acc[1][3], 0, 0, 0);
    }

    const int orow = (ln >> 4) * 4;
    #pragma unroll
    for (int rt = 0; rt < 2; rt++) {
        #pragma unroll
        for (int ct = 0; ct < 4; ct++) {
            const int o = ct * 16 + lr;
            #pragma unroll
            for (int q = 0; q < 4; q++) {
                const size_t row = (size_t)(m0 + wv * 32 + rt * 16 + orow + q);
                kanp[((size_t)ks * M_ + row) * 64 + o] = acc[rt][ct][q];
            }
        }
    }
}

// ---------------------------------------------------------------------------
// final: out[b][t][n][f] = sum_ks sum_o kanp[ks][m][o]*Wf[tf][o] + bf[tf]
// ---------------------------------------------------------------------------
__global__ __launch_bounds__(256) void final_kernel(
    const float* __restrict__ kanp,
    const float* __restrict__ Wf,
    const float* __restrict__ bf,
    float* __restrict__ out)
{
    __shared__ float At[64 * 68];  // [o][m]
    __shared__ float Bt[64 * 68];  // [o][tf]

    const int tid = threadIdx.x;
    const int tx  = tid & 15;
    const int ty  = tid >> 4;
    const int m0  = blockIdx.x * 64;
    const int tf0 = blockIdx.y * 64;

    const int r  = tid & 15;
    const int c4 = (tid >> 4) * 4;

    #pragma unroll
    for (int s = 0; s < 4; s++) {
        const int rw = r + s * 16;
        float4 k4 = *(const float4*)&kanp[(size_t)(m0 + rw) * 64 + c4];
        #pragma unroll
        for (int p = 1; p < KS_; p++) {
            const float4 kp = *(const float4*)&kanp[(size_t)p * M_ * 64 + (size_t)(m0 + rw) * 64 + c4];
            k4.x += kp.x; k4.y += kp.y; k4.z += kp.z; k4.w += kp.w;
        }
        At[(c4 + 0) * 68 + rw] = k4.x;
        At[(c4 + 1) * 68 + rw] = k4.y;
        At[(c4 + 2) * 68 + rw] = k4.z;
        At[(c4 + 3) * 68 + rw] = k4.w;
        const float4 w4 = *(const float4*)&Wf[(size_t)(tf0 + rw) * 64 + c4];
        Bt[(c4 + 0) * 68 + rw] = w4.x;
        Bt[(c4 + 1) * 68 + rw] = w4.y;
        Bt[(c4 + 2) * 68 + rw] = w4.z;
        Bt[(c4 + 3) * 68 + rw] = w4.w;
    }
    __syncthreads();

    float acc[4][4] = {};
    #pragma unroll 8
    for (int o = 0; o < 64; o++) {
        const float4 a = *(const float4*)&At[o * 68 + ty * 4];
        const float4 w = *(const float4*)&Bt[o * 68 + tx * 4];
        const float aarr[4] = {a.x, a.y, a.z, a.w};
        const float warr[4] = {w.x, w.y, w.z, w.w};
        #pragma unroll
        for (int p = 0; p < 4; p++)
            #pragma unroll
            for (int q = 0; q < 4; q++)
                acc[p][q] = fmaf(aarr[p], warr[q], acc[p][q]);
    }

    const int tf = tf0 + tx * 4;
    const float4 b4 = *(const float4*)&bf[tf];
    const int t  = tf >> 3;
    const int f0 = tf & 7;
    const int bb = m0 >> 9;
    const int n0 = (m0 & 511) + ty * 4;

    #pragma unroll
    for (int p = 0; p < 4; p++) {
        float4 o4 = make_float4(acc[p][0] + b4.x, acc[p][1] + b4.y,
                                acc[p][2] + b4.z, acc[p][3] + b4.w);
        *(float4*)&out[(size_t)bb * (T_ * N_ * F_)
                       + (size_t)t * (N_ * F_)
                       + (size_t)(n0 + p) * F_ + f0] = o4;
    }
}

// ---------------------------------------------------------------------------
extern "C" void kernel_launch(void* const* d_in, const int* in_sizes, int n_in,
                              void* d_out, int out_size, void* d_ws, size_t ws_size,
                              hipStream_t stream)
{
    const float* X      = (const float*)d_in[0];
    const float* Y      = (const float*)d_in[1];
    const float* Wx     = (const float*)d_in[2];
    const float* bx     = (const float*)d_in[3];
    const float* Wy     = (const float*)d_in[4];
    const float* by     = (const float*)d_in[5];
    const float* base_w = (const float*)d_in[6];
    const float* spline_w = (const float*)d_in[7];
    const float* spline_scaler = (const float*)d_in[8];
    const float* Wf     = (const float*)d_in[9];
    const float* bf     = (const float*)d_in[10];

    float* out = (float*)d_out;
    ushort_t* ht    = (ushort_t*)((char*)d_ws + HT_B);
    ushort_t* wq    = (ushort_t*)((char*)d_ws + WQ_B);
    ushort_t* wfrag = (ushort_t*)((char*)d_ws + WFRAG_B);
    float*    kanp  = (float*)((char*)d_ws + KANP_B);

    pack_wq<<<2304, 256, 0, stream>>>(base_w, spline_w, spline_scaler, wq);
    pack_wb<<<3072, 256, 0, stream>>>(Wx, Wy, wfrag);

    gemm_tanh_v4<<<dim3(M_ / 64, 2), 512, 0, stream>>>(X, Y, wfrag, bx, by, ht);

    kan_v3<<<dim3(M_ / RPB_, KS_), 256, 0, stream>>>(ht, wq, kanp);

    final_kernel<<<dim3(M_ / 64, TF_ / 64), 256, 0, stream>>>(kanp, Wf, bf, out);
}

// Round 5
// 179.491 us; speedup vs baseline: 4.4773x; 1.1075x over previous
//
#include <hip/hip_runtime.h>
#include <cmath>

#define B_    32
#define T_    96
#define N_    512
#define F_    8
#define TF_   768
#define HID_  512
#define M_    16384
#define KIN_  1024
#define KS_   8        // K-split for kan
#define RPB_  128      // rows per kan block

typedef short short8 __attribute__((ext_vector_type(8)));
typedef float f32x4  __attribute__((ext_vector_type(4)));
typedef unsigned int  uintx4 __attribute__((ext_vector_type(4)));
typedef unsigned long long ulongx2 __attribute__((ext_vector_type(2)));
typedef unsigned short      ushort_t;
typedef unsigned int        uint_t;
typedef unsigned long long  ulong_t;

// workspace byte offsets
#define HT_B     0ull                // bf16 ht[1024][16384]            = 33,554,432 B
#define WQ_B     33554432ull         // bf16 wq[8][9][4][4][64][8]      =  1,179,648 B
#define WFRAG_B  34734080ull         // bf16 wfrag[2][24][8][4][64][8]  =  1,572,864 B
#define KANP_B   36306944ull         // f32 kanp[8][16384][64]          = 33,554,432 B

static __device__ inline uint_t  fbits(float f){ return __builtin_bit_cast(uint_t, f); }
static __device__ inline ushort_t f2b(float f){
    uint_t u = fbits(f);
    return (ushort_t)((u + 0x7fffu + ((u >> 16) & 1u)) >> 16);
}
static __device__ inline float b2f(ushort_t h){ return __builtin_bit_cast(float, (uint_t)h << 16); }
static __device__ inline ulong_t pack4(float4 v){
    return (ulong_t)f2b(v.x) | ((ulong_t)f2b(v.y) << 16) |
           ((ulong_t)f2b(v.z) << 32) | ((ulong_t)f2b(v.w) << 48);
}
static __device__ inline float fast_tanh(float x){
    const float e = __expf(2.0f * x);
    return 1.0f - 2.0f / (e + 1.0f);
}

// ---------------------------------------------------------------------------
// pack_wq: KAN weights in MFMA B-fragment order (unchanged).
// ---------------------------------------------------------------------------
__global__ __launch_bounds__(256) void pack_wq(
    const float* __restrict__ base_w,
    const float* __restrict__ spline_w,
    const float* __restrict__ scaler,
    ushort_t* __restrict__ wq)
{
    const int e = blockIdx.x * 256 + threadIdx.x;   // 589824
    const int j    = e & 7;
    const int ln   = (e >> 3) & 63;
    const int ct   = (e >> 9) & 3;
    const int t    = (e >> 11) & 3;
    const int rest = e >> 13;        // 0..71
    const int ss   = rest % 9;
    const int ks   = rest / 9;
    const int o = ct * 16 + (ln & 15);
    const int g = ln >> 4;
    float v;
    if (ss < 8) {
        const int i = ks * 128 + ss * 16 + t * 4 + g;
        v = spline_w[(o * KIN_ + i) * 8 + j] * scaler[o * KIN_ + i];
    } else {
        const int i = ks * 128 + t * 32 + g * 8 + j;
        v = base_w[o * KIN_ + i];
    }
    wq[e] = f2b(v);
}

// ---------------------------------------------------------------------------
// pack_wb: Wx/Wy bf16 in MFMA B-fragment order, grouped by 64-col slices.
// wfrag[z][ks(24)][jg(8)][ct(4)][ln(64)][8]:
//   j = jg*64 + ct*16 + (ln&15), k = ks*32 + (ln>>4)*8 + jj
// ---------------------------------------------------------------------------
__global__ __launch_bounds__(256) void pack_wb(
    const float* __restrict__ Wx,
    const float* __restrict__ Wy,
    ushort_t* __restrict__ wfrag)
{
    const int e = blockIdx.x * 256 + threadIdx.x;   // 2*24*8*4*64*8 = 786432
    const int jj  = e & 7;
    const int ln  = (e >> 3) & 63;
    const int ct  = (e >> 9) & 3;
    const int jg  = (e >> 11) & 7;
    const int rest = e >> 14;        // 0..47
    const int ks  = rest % 24;
    const int z   = rest / 24;
    const int j = jg * 64 + ct * 16 + (ln & 15);
    const int k = ks * 32 + (ln >> 4) * 8 + jj;
    const float* W = z ? Wy : Wx;
    wfrag[e] = f2b(W[(size_t)j * TF_ + k]);
}

// ---------------------------------------------------------------------------
// gemm_tanh_v5: ht[jOff+j][m] = tanh( sum_k Xf[m,k]*W[j,k] + bias[j] )
// 256 threads (4 waves), BM=64, BN=256 (per block), BK=64.
// Wave = 64 rows x 64 cols (acc 4x4) -> B-frags read once per 64-row strip.
// LDS = 16KB: A-tile double-buffer only; epilogue reuses it in 2 passes.
// Grid (256 m-blocks, 2 ncol, 2 z) = 1024 blocks.
// ---------------------------------------------------------------------------
__global__ __launch_bounds__(256) void gemm_tanh_v5(
    const float* __restrict__ X, const float* __restrict__ Y,
    const ushort_t* __restrict__ wfrag,
    const float* __restrict__ bx, const float* __restrict__ by,
    ushort_t* __restrict__ ht)
{
    __shared__ __align__(16) char smem[16384];

    const int z = blockIdx.z;
    const float* Xs   = z ? Y  : X;
    const float* bias = z ? by : bx;
    const int jOff    = z ? HID_ : 0;
    const short8* wf  = (const short8*)wfrag + (size_t)z * 49152;

    const int tid = threadIdx.x;
    const int wv  = tid >> 6;          // 0..3
    const int ln  = tid & 63;
    const int lr  = ln & 15;
    const int hi  = ln >> 4;

    const int m0   = blockIdx.x * 64;
    const int ncol = blockIdx.y;
    const int jg64 = ncol * 4 + wv;    // global 64-col group (0..7)
    const int bb   = m0 >> 9;
    const int n0   = m0 & 511;

    // A staging: row = tid>>2 (0..63), two 16B k-chunks sc2, sc2+1
    const int srow = tid >> 2;
    const int sc2  = (tid & 3) * 2;
    const float* sbase = Xs + (size_t)bb * (T_ * N_ * F_)
                            + (size_t)(n0 + srow) * F_;

    f32x4 acc[4][4] = {};

    float4 pva0 = *(const float4*)(sbase + (size_t)sc2 * (N_ * F_));
    float4 pva1 = *(const float4*)(sbase + (size_t)sc2 * (N_ * F_) + 4);
    float4 pvb0 = *(const float4*)(sbase + (size_t)(sc2 + 1) * (N_ * F_));
    float4 pvb1 = *(const float4*)(sbase + (size_t)(sc2 + 1) * (N_ * F_) + 4);

    int p = 0;
    for (int kt = 0; kt < 12; kt++) {
        ulongx2 w0, w1;
        w0.x = pack4(pva0); w0.y = pack4(pva1);
        w1.x = pack4(pvb0); w1.y = pack4(pvb1);
        *(ulongx2*)(smem + p * 8192 + ((srow * 128 + sc2 * 16)       ^ ((srow & 7) << 4))) = w0;
        *(ulongx2*)(smem + p * 8192 + ((srow * 128 + (sc2 + 1) * 16) ^ ((srow & 7) << 4))) = w1;
        __syncthreads();

        if (kt < 11) {
            const float* nb = sbase + (size_t)((kt + 1) * 8 + sc2) * (N_ * F_);
            pva0 = *(const float4*)(nb);
            pva1 = *(const float4*)(nb + 4);
            pvb0 = *(const float4*)(nb + (N_ * F_));
            pvb1 = *(const float4*)(nb + (N_ * F_) + 4);
        }

        #pragma unroll
        for (int h = 0; h < 2; h++) {
            const int ks32 = kt * 2 + h;
            const short8* bp = wf + (size_t)((ks32 * 8 + jg64) * 4) * 64 + ln;
            const short8 b0 = bp[0], b1 = bp[64], b2 = bp[128], b3 = bp[192];
            short8 a[4];
            #pragma unroll
            for (int rt = 0; rt < 4; rt++) {
                const int ar = rt * 16 + lr;
                a[rt] = *(short8*)(smem + p * 8192 + ((ar * 128 + h * 64 + hi * 16) ^ ((ar & 7) << 4)));
            }
            #pragma unroll
            for (int rt = 0; rt < 4; rt++) {
                acc[rt][0] = __builtin_amdgcn_mfma_f32_16x16x32_bf16(a[rt], b0, acc[rt][0], 0, 0, 0);
                acc[rt][1] = __builtin_amdgcn_mfma_f32_16x16x32_bf16(a[rt], b1, acc[rt][1], 0, 0, 0);
                acc[rt][2] = __builtin_amdgcn_mfma_f32_16x16x32_bf16(a[rt], b2, acc[rt][2], 0, 0, 0);
                acc[rt][3] = __builtin_amdgcn_mfma_f32_16x16x32_bf16(a[rt], b3, acc[rt][3], 0, 0, 0);
            }
        }
        p ^= 1;
    }

    // epilogue: bias + tanh -> 2 passes through 16KB LDS -> coalesced ht stores
    __syncthreads();
    float bvv[4];
    #pragma unroll
    for (int ct = 0; ct < 4; ct++) bvv[ct] = bias[jg64 * 64 + ct * 16 + lr];

    #pragma unroll
    for (int pass = 0; pass < 2; pass++) {
        if ((wv >> 1) == pass) {
            const int h2 = wv & 1;
            #pragma unroll
            for (int ct = 0; ct < 4; ct++) {
                const int jrow = h2 * 64 + ct * 16 + lr;   // LDS row 0..127
                #pragma unroll
                for (int rt = 0; rt < 4; rt++) {
                    const f32x4 v = acc[rt][ct];
                    float4 tv;
                    tv.x = fast_tanh(v[0] + bvv[ct]);
                    tv.y = fast_tanh(v[1] + bvv[ct]);
                    tv.z = fast_tanh(v[2] + bvv[ct]);
                    tv.w = fast_tanh(v[3] + bvv[ct]);
                    *(ulong_t*)(smem + ((jrow * 128 + (rt * 16 + hi * 4) * 2) ^ ((jrow & 7) << 4))) = pack4(tv);
                }
            }
        }
        __syncthreads();
        {
            const int jr = tid >> 1;               // 0..127
            const int cb = (tid & 1) * 64;         // byte base within 128B row
            const int jglob = jOff + ncol * 256 + pass * 128 + jr;
            ushort_t* dst = ht + (size_t)jglob * M_ + m0 + cb / 2;
            #pragma unroll
            for (int u = 0; u < 4; u++) {
                short8 val = *(short8*)(smem + ((jr * 128 + cb + u * 16) ^ ((jr & 7) << 4)));
                *(short8*)(dst + u * 8) = val;
            }
        }
        __syncthreads();
    }
}

// ---------------------------------------------------------------------------
// kan_v3: zero-LDS (unchanged).
// ---------------------------------------------------------------------------
static __device__ inline short8 eval_bases(float x)
{
    const float v = fmaf(x, 2.5f, 2.5f);
    float sf = floorf(v);
    sf = fminf(fmaxf(sf, 0.0f), 4.0f);
    const float u = v - sf;
    const int si = (int)sf;
    const float u2 = u * u, u3 = u2 * u;
    const float omu = 1.0f - u;
    const float omu3 = omu * omu * omu;
    const float Bb0 = omu3 * (1.0f / 6.0f);
    const float Bb3 = u3 * (1.0f / 6.0f);
    const float Bb1 = fmaf(0.5f, u3, 2.0f / 3.0f) - u2;
    const float Bb2 = 1.0f - Bb0 - Bb1 - Bb3;
    const uint_t d0 = (fbits(Bb0) >> 16) | (fbits(Bb1) & 0xffff0000u);
    const uint_t d1 = (fbits(Bb2) >> 16) | (fbits(Bb3) & 0xffff0000u);
    const ulong_t P = (ulong_t)d0 | ((ulong_t)d1 << 32);
    const int sh = si << 4;
    const ulong_t Plo = P << (sh & 63);
    const ulong_t Phi = P >> ((64 - sh) & 63);
    ulongx2 pr;
    pr.x = (si == 4) ? 0ull : Plo;
    pr.y = (si == 0) ? 0ull : ((si == 4) ? P : Phi);
    return __builtin_bit_cast(short8, pr);
}

static __device__ inline short8 eval_silu8(const ushort_t* __restrict__ ht, int ib0, size_t r)
{
    uintx4 d;
    #pragma unroll
    for (int jj = 0; jj < 4; jj++) {
        const float x0 = b2f(ht[(size_t)(ib0 + 2 * jj)     * M_ + r]);
        const float x1 = b2f(ht[(size_t)(ib0 + 2 * jj + 1) * M_ + r]);
        const float s0 = x0 / (1.0f + __expf(-x0));
        const float s1 = x1 / (1.0f + __expf(-x1));
        d[jj] = (fbits(s0) >> 16) | (fbits(s1) & 0xffff0000u);
    }
    return __builtin_bit_cast(short8, d);
}

__global__ __launch_bounds__(256) void kan_v3(
    const ushort_t* __restrict__ ht,
    const ushort_t* __restrict__ wq,
    float* __restrict__ kanp)
{
    const int tid = threadIdx.x;
    const int wv  = tid >> 6;
    const int ln  = tid & 63;
    const int g   = ln >> 4;
    const int lr  = ln & 15;
    const int m0  = blockIdx.x * RPB_;
    const int ks  = blockIdx.y;
    const int iB  = ks * (KIN_ / KS_);
    const size_t r0 = (size_t)(m0 + wv * 32 + lr);
    const size_t r1 = r0 + 16;

    const short8* wqf = (const short8*)wq + (size_t)ks * 9216 + ln;

    f32x4 acc[2][4] = {};

    for (int ss = 0; ss < 8; ss++) {
        #pragma unroll
        for (int t = 0; t < 4; t++) {
            const short8* bp = wqf + (size_t)(ss * 4 + t) * 256;
            const short8 b0 = bp[0], b1 = bp[64], b2 = bp[128], b3 = bp[192];
            const int i = iB + ss * 16 + t * 4 + g;
            const short8 a0 = eval_bases(b2f(ht[(size_t)i * M_ + r0]));
            const short8 a1 = eval_bases(b2f(ht[(size_t)i * M_ + r1]));
            acc[0][0] = __builtin_amdgcn_mfma_f32_16x16x32_bf16(a0, b0, acc[0][0], 0, 0, 0);
            acc[0][1] = __builtin_amdgcn_mfma_f32_16x16x32_bf16(a0, b1, acc[0][1], 0, 0, 0);
            acc[0][2] = __builtin_amdgcn_mfma_f32_16x16x32_bf16(a0, b2, acc[0][2], 0, 0, 0);
            acc[0][3] = __builtin_amdgcn_mfma_f32_16x16x32_bf16(a0, b3, acc[0][3], 0, 0, 0);
            acc[1][0] = __builtin_amdgcn_mfma_f32_16x16x32_bf16(a1, b0, acc[1][0], 0, 0, 0);
            acc[1][1] = __builtin_amdgcn_mfma_f32_16x16x32_bf16(a1, b1, acc[1][1], 0, 0, 0);
            acc[1][2] = __builtin_amdgcn_mfma_f32_16x16x32_bf16(a1, b2, acc[1][2], 0, 0, 0);
            acc[1][3] = __builtin_amdgcn_mfma_f32_16x16x32_bf16(a1, b3, acc[1][3], 0, 0, 0);
        }
    }
    #pragma unroll
    for (int t = 0; t < 4; t++) {
        const short8* bp = wqf + (size_t)(32 + t) * 256;
        const short8 b0 = bp[0], b1 = bp[64], b2 = bp[128], b3 = bp[192];
        const int ib0 = iB + t * 32 + g * 8;
        const short8 a0 = eval_silu8(ht, ib0, r0);
        const short8 a1 = eval_silu8(ht, ib0, r1);
        acc[0][0] = __builtin_amdgcn_mfma_f32_16x16x32_bf16(a0, b0, acc[0][0], 0, 0, 0);
        acc[0][1] = __builtin_amdgcn_mfma_f32_16x16x32_bf16(a0, b1, acc[0][1], 0, 0, 0);
        acc[0][2] = __builtin_amdgcn_mfma_f32_16x16x32_bf16(a0, b2, acc[0][2], 0, 0, 0);
        acc[0][3] = __builtin_amdgcn_mfma_f32_16x16x32_bf16(a0, b3, acc[0][3], 0, 0, 0);
        acc[1][0] = __builtin_amdgcn_mfma_f32_16x16x32_bf16(a1, b0, acc[1][0], 0, 0, 0);
        acc[1][1] = __builtin_amdgcn_mfma_f32_16x16x32_bf16(a1, b1, acc[1][1], 0, 0, 0);
        acc[1][2] = __builtin_amdgcn_mfma_f32_16x16x32_bf16(a1, b2, acc[1][2], 0, 0, 0);
        acc[1][3] = __builtin_amdgcn_mfma_f32_16x16x32_bf16(a1, b3, acc[1][3], 0, 0, 0);
    }

    const int orow = (ln >> 4) * 4;
    #pragma unroll
    for (int rt = 0; rt < 2; rt++) {
        #pragma unroll
        for (int ct = 0; ct < 4; ct++) {
            const int o = ct * 16 + lr;
            #pragma unroll
            for (int q = 0; q < 4; q++) {
                const size_t row = (size_t)(m0 + wv * 32 + rt * 16 + orow + q);
                kanp[((size_t)ks * M_ + row) * 64 + o] = acc[rt][ct][q];
            }
        }
    }
}

// ---------------------------------------------------------------------------
// final: out[b][t][n][f] = sum_ks sum_o kanp[ks][m][o]*Wf[tf][o] + bf[tf]
// ---------------------------------------------------------------------------
__global__ __launch_bounds__(256) void final_kernel(
    const float* __restrict__ kanp,
    const float* __restrict__ Wf,
    const float* __restrict__ bf,
    float* __restrict__ out)
{
    __shared__ float At[64 * 68];  // [o][m]
    __shared__ float Bt[64 * 68];  // [o][tf]

    const int tid = threadIdx.x;
    const int tx  = tid & 15;
    const int ty  = tid >> 4;
    const int m0  = blockIdx.x * 64;
    const int tf0 = blockIdx.y * 64;

    const int r  = tid & 15;
    const int c4 = (tid >> 4) * 4;

    #pragma unroll
    for (int s = 0; s < 4; s++) {
        const int rw = r + s * 16;
        float4 k4 = *(const float4*)&kanp[(size_t)(m0 + rw) * 64 + c4];
        #pragma unroll
        for (int p = 1; p < KS_; p++) {
            const float4 kp = *(const float4*)&kanp[(size_t)p * M_ * 64 + (size_t)(m0 + rw) * 64 + c4];
            k4.x += kp.x; k4.y += kp.y; k4.z += kp.z; k4.w += kp.w;
        }
        At[(c4 + 0) * 68 + rw] = k4.x;
        At[(c4 + 1) * 68 + rw] = k4.y;
        At[(c4 + 2) * 68 + rw] = k4.z;
        At[(c4 + 3) * 68 + rw] = k4.w;
        const float4 w4 = *(const float4*)&Wf[(size_t)(tf0 + rw) * 64 + c4];
        Bt[(c4 + 0) * 68 + rw] = w4.x;
        Bt[(c4 + 1) * 68 + rw] = w4.y;
        Bt[(c4 + 2) * 68 + rw] = w4.z;
        Bt[(c4 + 3) * 68 + rw] = w4.w;
    }
    __syncthreads();

    float acc[4][4] = {};
    #pragma unroll 8
    for (int o = 0; o < 64; o++) {
        const float4 a = *(const float4*)&At[o * 68 + ty * 4];
        const float4 w = *(const float4*)&Bt[o * 68 + tx * 4];
        const float aarr[4] = {a.x, a.y, a.z, a.w};
        const float warr[4] = {w.x, w.y, w.z, w.w};
        #pragma unroll
        for (int p = 0; p < 4; p++)
            #pragma unroll
            for (int q = 0; q < 4; q++)
                acc[p][q] = fmaf(aarr[p], warr[q], acc[p][q]);
    }

    const int tf = tf0 + tx * 4;
    const float4 b4 = *(const float4*)&bf[tf];
    const int t  = tf >> 3;
    const int f0 = tf & 7;
    const int bb = m0 >> 9;
    const int n0 = (m0 & 511) + ty * 4;

    #pragma unroll
    for (int p = 0; p < 4; p++) {
        float4 o4 = make_float4(acc[p][0] + b4.x, acc[p][1] + b4.y,
                                acc[p][2] + b4.z, acc[p][3] + b4.w);
        *(float4*)&out[(size_t)bb * (T_ * N_ * F_)
                       + (size_t)t * (N_ * F_)
                       + (size_t)(n0 + p) * F_ + f0] = o4;
    }
}

// ---------------------------------------------------------------------------
extern "C" void kernel_launch(void* const* d_in, const int* in_sizes, int n_in,
                              void* d_out, int out_size, void* d_ws, size_t ws_size,
                              hipStream_t stream)
{
    const float* X      = (const float*)d_in[0];
    const float* Y      = (const float*)d_in[1];
    const float* Wx     = (const float*)d_in[2];
    const float* bx     = (const float*)d_in[3];
    const float* Wy     = (const float*)d_in[4];
    const float* by     = (const float*)d_in[5];
    const float* base_w = (const float*)d_in[6];
    const float* spline_w = (const float*)d_in[7];
    const float* spline_scaler = (const float*)d_in[8];
    const float* Wf     = (const float*)d_in[9];
    const float* bf     = (const float*)d_in[10];

    float* out = (float*)d_out;
    ushort_t* ht    = (ushort_t*)((char*)d_ws + HT_B);
    ushort_t* wq    = (ushort_t*)((char*)d_ws + WQ_B);
    ushort_t* wfrag = (ushort_t*)((char*)d_ws + WFRAG_B);
    float*    kanp  = (float*)((char*)d_ws + KANP_B);

    pack_wq<<<2304, 256, 0, stream>>>(base_w, spline_w, spline_scaler, wq);
    pack_wb<<<3072, 256, 0, stream>>>(Wx, Wy, wfrag);

    gemm_tanh_v5<<<dim3(M_ / 64, 2, 2), 256, 0, stream>>>(X, Y, wfrag, bx, by, ht);

    kan_v3<<<dim3(M_ / RPB_, KS_), 256, 0, stream>>>(ht, wq, kanp);

    final_kernel<<<dim3(M_ / 64, TF_ / 64), 256, 0, stream>>>(kanp, Wf, bf, out);
}

// Round 6
// 165.267 us; speedup vs baseline: 4.8626x; 1.0861x over previous
//
#include <hip/hip_runtime.h>
#include <cmath>

#define B_    32
#define T_    96
#define N_    512
#define F_    8
#define TF_   768
#define HID_  512
#define M_    16384
#define KIN_  1024
#define KS_   8        // K-split for kan
#define RPB_  128      // rows per kan block

typedef short short8 __attribute__((ext_vector_type(8)));
typedef float f32x4  __attribute__((ext_vector_type(4)));
typedef unsigned int  uintx4 __attribute__((ext_vector_type(4)));
typedef unsigned long long ulongx2 __attribute__((ext_vector_type(2)));
typedef unsigned short      ushort_t;
typedef unsigned int        uint_t;
typedef unsigned long long  ulong_t;

// workspace byte offsets (total 69,861,376 B — same footprint as round 5)
#define HT_B     0ull                // bf16 ht[1024][16384]            = 33,554,432 B
#define WQ_B     33554432ull         // bf16 wq[8][9][4][4][64][8]      =  1,179,648 B
#define WB_B     34734080ull         // bf16 wb[1024][768]              =  1,572,864 B
#define KANP_B   36306944ull         // f32 kanp[8][16384][64]          = 33,554,432 B

static __device__ inline uint_t  fbits(float f){ return __builtin_bit_cast(uint_t, f); }
static __device__ inline ushort_t f2b(float f){
    uint_t u = fbits(f);
    return (ushort_t)((u + 0x7fffu + ((u >> 16) & 1u)) >> 16);
}
static __device__ inline float b2f(ushort_t h){ return __builtin_bit_cast(float, (uint_t)h << 16); }
static __device__ inline ulong_t pack4(float4 v){
    return (ulong_t)f2b(v.x) | ((ulong_t)f2b(v.y) << 16) |
           ((ulong_t)f2b(v.z) << 32) | ((ulong_t)f2b(v.w) << 48);
}
static __device__ inline float fast_tanh(float x){
    const float e = __expf(2.0f * x);
    return 1.0f - 2.0f / (e + 1.0f);
}
static __device__ inline void gload_lds16(const void* g, void* l){
    __builtin_amdgcn_global_load_lds(
        (const __attribute__((address_space(1))) unsigned int*)g,
        (__attribute__((address_space(3))) unsigned int*)l, 16, 0, 0);
}

// ---------------------------------------------------------------------------
// pack_wq: KAN weights in MFMA B-fragment order (unchanged).
// ---------------------------------------------------------------------------
__global__ __launch_bounds__(256) void pack_wq(
    const float* __restrict__ base_w,
    const float* __restrict__ spline_w,
    const float* __restrict__ scaler,
    ushort_t* __restrict__ wq)
{
    const int e = blockIdx.x * 256 + threadIdx.x;   // 589824
    const int j    = e & 7;
    const int ln   = (e >> 3) & 63;
    const int ct   = (e >> 9) & 3;
    const int t    = (e >> 11) & 3;
    const int rest = e >> 13;        // 0..71
    const int ss   = rest % 9;
    const int ks   = rest / 9;
    const int o = ct * 16 + (ln & 15);
    const int g = ln >> 4;
    float v;
    if (ss < 8) {
        const int i = ks * 128 + ss * 16 + t * 4 + g;
        v = spline_w[(o * KIN_ + i) * 8 + j] * scaler[o * KIN_ + i];
    } else {
        const int i = ks * 128 + t * 32 + g * 8 + j;
        v = base_w[o * KIN_ + i];
    }
    wq[e] = f2b(v);
}

// ---------------------------------------------------------------------------
// pack_wb2: wb[1024][768] bf16, rows 0..511 = Wx, 512..1023 = Wy (row-major).
// e = j*768+k, so src is just Wx[e] / Wy[e - 512*768].
// ---------------------------------------------------------------------------
__global__ __launch_bounds__(256) void pack_wb2(
    const float* __restrict__ Wx,
    const float* __restrict__ Wy,
    ushort_t* __restrict__ wb)
{
    const int e = blockIdx.x * 256 + threadIdx.x;   // 786432
    const float v = (e < 512 * TF_) ? Wx[e] : Wy[e - 512 * TF_];
    wb[e] = f2b(v);
}

// ---------------------------------------------------------------------------
// gemm_tanh_v6 (m97-pattern): ht[j][m] = tanh( sum_k Xf[m,k]*wb[j,k] + bias )
// M=16384, N=1024 (X/Y combined), K=768.  128x128 tile, BK=64, 4 waves
// (each 64m x 64j, acc 4x4).  B staged via global_load_lds (linear dest,
// inverse-swizzled per-lane source); A gathered fp32 (contiguous 2KB/instr),
// converted in regs, ds_write_b64 swizzled; A-prefetch overlaps compute.
// LDS 32KB single-buffer, 2 barriers/K-step, reused for epilogue transpose.
// ---------------------------------------------------------------------------
__global__ __launch_bounds__(256) void gemm_tanh_v6(
    const float* __restrict__ X, const float* __restrict__ Y,
    const ushort_t* __restrict__ wb,
    const float* __restrict__ bx, const float* __restrict__ by,
    ushort_t* __restrict__ ht)
{
    __shared__ __align__(16) char smem[32768];   // A:[0,16K) B:[16K,32K)

    const int tid = threadIdx.x;
    const int wv  = tid >> 6;
    const int ln  = tid & 63;
    const int lr  = ln & 15;
    const int hi  = ln >> 4;

    const int m0 = blockIdx.x * 128;
    const int j0 = blockIdx.y * 128;             // global j (0..1023)
    const int bb = m0 >> 9;
    const int n0 = m0 & 511;
    const float* Xs   = (j0 >= 512) ? Y  : X;
    const float* bias = (j0 >= 512) ? by : bx;
    const int jl0     = j0 & 511;

    // A staging: row = tid>>1 (0..127), f-half = tid&1  (loads are contiguous)
    const int arow = tid >> 1;
    const int fh   = tid & 1;
    const float* abase = Xs + (size_t)bb * (T_ * N_ * F_)
                            + (size_t)(n0 + arow) * F_ + fh * 4;

    // B gload_lds roles: call s covers LDS rows (s*4+wv)*8 .. +8
    int brow[4], bksrc[4];
    #pragma unroll
    for (int s = 0; s < 4; s++) {
        brow[s]  = (s * 4 + wv) * 8 + (ln >> 3);
        bksrc[s] = ((ln & 7) ^ (brow[s] & 7)) * 8;   // element offset
    }

    f32x4 acc[4][4] = {};

    // prologue: A regs for kt=0
    float4 areg[8];
    #pragma unroll
    for (int u = 0; u < 8; u++)
        areg[u] = *(const float4*)(abase + (size_t)u * (N_ * F_));

    for (int kt = 0; kt < 12; kt++) {
        __syncthreads();   // previous compute's LDS reads done
        // A: pack + 8x ds_write_b64 (slot u^(row&7), 8B half fh)
        #pragma unroll
        for (int u = 0; u < 8; u++) {
            *(ulong_t*)(smem + arow * 128 + ((u ^ (arow & 7)) * 16) + fh * 8)
                = pack4(areg[u]);
        }
        // B: 4x global_load_lds dwordx4 per wave (16KB total)
        #pragma unroll
        for (int s = 0; s < 4; s++) {
            const ushort_t* src = wb + (size_t)(j0 + brow[s]) * TF_ + kt * 64 + bksrc[s];
            gload_lds16(src, smem + 16384 + (s * 4 + wv) * 1024 + ln * 16);
        }
        __syncthreads();   // A visible + B landed (compiler drains vmcnt/lgkm)

        // prefetch next A tile (stays in flight across compute)
        if (kt < 11) {
            #pragma unroll
            for (int u = 0; u < 8; u++)
                areg[u] = *(const float4*)(abase + (size_t)((kt + 1) * 8 + u) * (N_ * F_));
        }

        const int mhalf = (wv >> 1) * 64;
        const int jhalf = (wv & 1) * 64;
        #pragma unroll
        for (int h = 0; h < 2; h++) {
            const int g = h * 4 + hi;            // k-chunk index (8 bf16 each)
            short8 a[4], b[4];
            #pragma unroll
            for (int rt = 0; rt < 4; rt++) {
                const int r = mhalf + rt * 16 + lr;
                a[rt] = *(short8*)(smem + r * 128 + ((g ^ (r & 7)) * 16));
            }
            #pragma unroll
            for (int ct = 0; ct < 4; ct++) {
                const int r = jhalf + ct * 16 + lr;
                b[ct] = *(short8*)(smem + 16384 + r * 128 + ((g ^ (r & 7)) * 16));
            }
            #pragma unroll
            for (int rt = 0; rt < 4; rt++)
                #pragma unroll
                for (int ct = 0; ct < 4; ct++)
                    acc[rt][ct] = __builtin_amdgcn_mfma_f32_16x16x32_bf16(
                        a[rt], b[ct], acc[rt][ct], 0, 0, 0);
        }
    }

    // epilogue: bias + tanh -> bf16 LDS [j 128][m 128] (16B-slot ^ (j&15)) -> ht
    __syncthreads();
    {
        const int mhalf = (wv >> 1) * 64;
        const int jhalf = (wv & 1) * 64;
        #pragma unroll
        for (int ct = 0; ct < 4; ct++) {
            const int j = jhalf + ct * 16 + lr;
            const float bvv = bias[jl0 + j];
            #pragma unroll
            for (int rt = 0; rt < 4; rt++) {
                const f32x4 v = acc[rt][ct];
                float4 tv;
                tv.x = fast_tanh(v[0] + bvv);
                tv.y = fast_tanh(v[1] + bvv);
                tv.z = fast_tanh(v[2] + bvv);
                tv.w = fast_tanh(v[3] + bvv);
                const int slot = (mhalf >> 3) + rt * 2 + (hi >> 1);  // 16B slot
                *(ulong_t*)(smem + j * 256 + ((slot ^ (j & 15)) * 16) + (hi & 1) * 8)
                    = pack4(tv);
            }
        }
    }
    __syncthreads();
    {
        const int j    = tid >> 1;           // 0..127
        const int half = tid & 1;
        ushort_t* dst = ht + (size_t)(j0 + j) * M_ + m0 + half * 64;
        #pragma unroll
        for (int w = 0; w < 8; w++) {
            const int slot = half * 8 + w;
            short8 val = *(short8*)(smem + j * 256 + ((slot ^ (j & 15)) * 16));
            *(short8*)(dst + w * 8) = val;
        }
    }
}

// ---------------------------------------------------------------------------
// kan_v3: zero-LDS (unchanged).
// ---------------------------------------------------------------------------
static __device__ inline short8 eval_bases(float x)
{
    const float v = fmaf(x, 2.5f, 2.5f);
    float sf = floorf(v);
    sf = fminf(fmaxf(sf, 0.0f), 4.0f);
    const float u = v - sf;
    const int si = (int)sf;
    const float u2 = u * u, u3 = u2 * u;
    const float omu = 1.0f - u;
    const float omu3 = omu * omu * omu;
    const float Bb0 = omu3 * (1.0f / 6.0f);
    const float Bb3 = u3 * (1.0f / 6.0f);
    const float Bb1 = fmaf(0.5f, u3, 2.0f / 3.0f) - u2;
    const float Bb2 = 1.0f - Bb0 - Bb1 - Bb3;
    const uint_t d0 = (fbits(Bb0) >> 16) | (fbits(Bb1) & 0xffff0000u);
    const uint_t d1 = (fbits(Bb2) >> 16) | (fbits(Bb3) & 0xffff0000u);
    const ulong_t P = (ulong_t)d0 | ((ulong_t)d1 << 32);
    const int sh = si << 4;
    const ulong_t Plo = P << (sh & 63);
    const ulong_t Phi = P >> ((64 - sh) & 63);
    ulongx2 pr;
    pr.x = (si == 4) ? 0ull : Plo;
    pr.y = (si == 0) ? 0ull : ((si == 4) ? P : Phi);
    return __builtin_bit_cast(short8, pr);
}

static __device__ inline short8 eval_silu8(const ushort_t* __restrict__ ht, int ib0, size_t r)
{
    uintx4 d;
    #pragma unroll
    for (int jj = 0; jj < 4; jj++) {
        const float x0 = b2f(ht[(size_t)(ib0 + 2 * jj)     * M_ + r]);
        const float x1 = b2f(ht[(size_t)(ib0 + 2 * jj + 1) * M_ + r]);
        const float s0 = x0 / (1.0f + __expf(-x0));
        const float s1 = x1 / (1.0f + __expf(-x1));
        d[jj] = (fbits(s0) >> 16) | (fbits(s1) & 0xffff0000u);
    }
    return __builtin_bit_cast(short8, d);
}

__global__ __launch_bounds__(256) void kan_v3(
    const ushort_t* __restrict__ ht,
    const ushort_t* __restrict__ wq,
    float* __restrict__ kanp)
{
    const int tid = threadIdx.x;
    const int wv  = tid >> 6;
    const int ln  = tid & 63;
    const int g   = ln >> 4;
    const int lr  = ln & 15;
    const int m0  = blockIdx.x * RPB_;
    const int ks  = blockIdx.y;
    const int iB  = ks * (KIN_ / KS_);
    const size_t r0 = (size_t)(m0 + wv * 32 + lr);
    const size_t r1 = r0 + 16;

    const short8* wqf = (const short8*)wq + (size_t)ks * 9216 + ln;

    f32x4 acc[2][4] = {};

    for (int ss = 0; ss < 8; ss++) {
        #pragma unroll
        for (int t = 0; t < 4; t++) {
            const short8* bp = wqf + (size_t)(ss * 4 + t) * 256;
            const short8 b0 = bp[0], b1 = bp[64], b2 = bp[128], b3 = bp[192];
            const int i = iB + ss * 16 + t * 4 + g;
            const short8 a0 = eval_bases(b2f(ht[(size_t)i * M_ + r0]));
            const short8 a1 = eval_bases(b2f(ht[(size_t)i * M_ + r1]));
            acc[0][0] = __builtin_amdgcn_mfma_f32_16x16x32_bf16(a0, b0, acc[0][0], 0, 0, 0);
            acc[0][1] = __builtin_amdgcn_mfma_f32_16x16x32_bf16(a0, b1, acc[0][1], 0, 0, 0);
            acc[0][2] = __builtin_amdgcn_mfma_f32_16x16x32_bf16(a0, b2, acc[0][2], 0, 0, 0);
            acc[0][3] = __builtin_amdgcn_mfma_f32_16x16x32_bf16(a0, b3, acc[0][3], 0, 0, 0);
            acc[1][0] = __builtin_amdgcn_mfma_f32_16x16x32_bf16(a1, b0, acc[1][0], 0, 0, 0);
            acc[1][1] = __builtin_amdgcn_mfma_f32_16x16x32_bf16(a1, b1, acc[1][1], 0, 0, 0);
            acc[1][2] = __builtin_amdgcn_mfma_f32_16x16x32_bf16(a1, b2, acc[1][2], 0, 0, 0);
            acc[1][3] = __builtin_amdgcn_mfma_f32_16x16x32_bf16(a1, b3, acc[1][3], 0, 0, 0);
        }
    }
    #pragma unroll
    for (int t = 0; t < 4; t++) {
        const short8* bp = wqf + (size_t)(32 + t) * 256;
        const short8 b0 = bp[0], b1 = bp[64], b2 = bp[128], b3 = bp[192];
        const int ib0 = iB + t * 32 + g * 8;
        const short8 a0 = eval_silu8(ht, ib0, r0);
        const short8 a1 = eval_silu8(ht, ib0, r1);
        acc[0][0] = __builtin_amdgcn_mfma_f32_16x16x32_bf16(a0, b0, acc[0][0], 0, 0, 0);
        acc[0][1] = __builtin_amdgcn_mfma_f32_16x16x32_bf16(a0, b1, acc[0][1], 0, 0, 0);
        acc[0][2] = __builtin_amdgcn_mfma_f32_16x16x32_bf16(a0, b2, acc[0][2], 0, 0, 0);
        acc[0][3] = __builtin_amdgcn_mfma_f32_16x16x32_bf16(a0, b3, acc[0][3], 0, 0, 0);
        acc[1][0] = __builtin_amdgcn_mfma_f32_16x16x32_bf16(a1, b0, acc[1][0], 0, 0, 0);
        acc[1][1] = __builtin_amdgcn_mfma_f32_16x16x32_bf16(a1, b1, acc[1][1], 0, 0, 0);
        acc[1][2] = __builtin_amdgcn_mfma_f32_16x16x32_bf16(a1, b2, acc[1][2], 0, 0, 0);
        acc[1][3] = __builtin_amdgcn_mfma_f32_16x16x32_bf16(a1, b3, acc[1][3], 0, 0, 0);
    }

    const int orow = (ln >> 4) * 4;
    #pragma unroll
    for (int rt = 0; rt < 2; rt++) {
        #pragma unroll
        for (int ct = 0; ct < 4; ct++) {
            const int o = ct * 16 + lr;
            #pragma unroll
            for (int q = 0; q < 4; q++) {
                const size_t row = (size_t)(m0 + wv * 32 + rt * 16 + orow + q);
                kanp[((size_t)ks * M_ + row) * 64 + o] = acc[rt][ct][q];
            }
        }
    }
}

// ---------------------------------------------------------------------------
// final: out[b][t][n][f] = sum_ks sum_o kanp[ks][m][o]*Wf[tf][o] + bf[tf]
// ---------------------------------------------------------------------------
__global__ __launch_bounds__(256) void final_kernel(
    const float* __restrict__ kanp,
    const float* __restrict__ Wf,
    const float* __restrict__ bf,
    float* __restrict__ out)
{
    __shared__ float At[64 * 68];  // [o][m]
    __shared__ float Bt[64 * 68];  // [o][tf]

    const int tid = threadIdx.x;
    const int tx  = tid & 15;
    const int ty  = tid >> 4;
    const int m0  = blockIdx.x * 64;
    const int tf0 = blockIdx.y * 64;

    const int r  = tid & 15;
    const int c4 = (tid >> 4) * 4;

    #pragma unroll
    for (int s = 0; s < 4; s++) {
        const int rw = r + s * 16;
        float4 k4 = *(const float4*)&kanp[(size_t)(m0 + rw) * 64 + c4];
        #pragma unroll
        for (int p = 1; p < KS_; p++) {
            const float4 kp = *(const float4*)&kanp[(size_t)p * M_ * 64 + (size_t)(m0 + rw) * 64 + c4];
            k4.x += kp.x; k4.y += kp.y; k4.z += kp.z; k4.w += kp.w;
        }
        At[(c4 + 0) * 68 + rw] = k4.x;
        At[(c4 + 1) * 68 + rw] = k4.y;
        At[(c4 + 2) * 68 + rw] = k4.z;
        At[(c4 + 3) * 68 + rw] = k4.w;
        const float4 w4 = *(const float4*)&Wf[(size_t)(tf0 + rw) * 64 + c4];
        Bt[(c4 + 0) * 68 + rw] = w4.x;
        Bt[(c4 + 1) * 68 + rw] = w4.y;
        Bt[(c4 + 2) * 68 + rw] = w4.z;
        Bt[(c4 + 3) * 68 + rw] = w4.w;
    }
    __syncthreads();

    float acc[4][4] = {};
    #pragma unroll 8
    for (int o = 0; o < 64; o++) {
        const float4 a = *(const float4*)&At[o * 68 + ty * 4];
        const float4 w = *(const float4*)&Bt[o * 68 + tx * 4];
        const float aarr[4] = {a.x, a.y, a.z, a.w};
        const float warr[4] = {w.x, w.y, w.z, w.w};
        #pragma unroll
        for (int p = 0; p < 4; p++)
            #pragma unroll
            for (int q = 0; q < 4; q++)
                acc[p][q] = fmaf(aarr[p], warr[q], acc[p][q]);
    }

    const int tf = tf0 + tx * 4;
    const float4 b4 = *(const float4*)&bf[tf];
    const int t  = tf >> 3;
    const int f0 = tf & 7;
    const int bb = m0 >> 9;
    const int n0 = (m0 & 511) + ty * 4;

    #pragma unroll
    for (int p = 0; p < 4; p++) {
        float4 o4 = make_float4(acc[p][0] + b4.x, acc[p][1] + b4.y,
                                acc[p][2] + b4.z, acc[p][3] + b4.w);
        *(float4*)&out[(size_t)bb * (T_ * N_ * F_)
                       + (size_t)t * (N_ * F_)
                       + (size_t)(n0 + p) * F_ + f0] = o4;
    }
}

// ---------------------------------------------------------------------------
extern "C" void kernel_launch(void* const* d_in, const int* in_sizes, int n_in,
                              void* d_out, int out_size, void* d_ws, size_t ws_size,
                              hipStream_t stream)
{
    const float* X      = (const float*)d_in[0];
    const float* Y      = (const float*)d_in[1];
    const float* Wx     = (const float*)d_in[2];
    const float* bx     = (const float*)d_in[3];
    const float* Wy     = (const float*)d_in[4];
    const float* by     = (const float*)d_in[5];
    const float* base_w = (const float*)d_in[6];
    const float* spline_w = (const float*)d_in[7];
    const float* spline_scaler = (const float*)d_in[8];
    const float* Wf     = (const float*)d_in[9];
    const float* bf     = (const float*)d_in[10];

    float* out = (float*)d_out;
    ushort_t* ht   = (ushort_t*)((char*)d_ws + HT_B);
    ushort_t* wq   = (ushort_t*)((char*)d_ws + WQ_B);
    ushort_t* wb   = (ushort_t*)((char*)d_ws + WB_B);
    float*    kanp = (float*)((char*)d_ws + KANP_B);

    pack_wq<<<2304, 256, 0, stream>>>(base_w, spline_w, spline_scaler, wq);
    pack_wb2<<<3072, 256, 0, stream>>>(Wx, Wy, wb);

    gemm_tanh_v6<<<dim3(M_ / 128, 8), 256, 0, stream>>>(X, Y, wb, bx, by, ht);

    kan_v3<<<dim3(M_ / RPB_, KS_), 256, 0, stream>>>(ht, wq, kanp);

    final_kernel<<<dim3(M_ / 64, TF_ / 64), 256, 0, stream>>>(kanp, Wf, bf, out);
}

// Round 7
// 146.413 us; speedup vs baseline: 5.4888x; 1.1288x over previous
//
#include <hip/hip_runtime.h>
#include <cmath>

#define B_    32
#define T_    96
#define N_    512
#define F_    8
#define TF_   768
#define HID_  512
#define M_    16384
#define KIN_  1024
#define KS_   4        // K-split for kan

typedef short short8 __attribute__((ext_vector_type(8)));
typedef float f32x4  __attribute__((ext_vector_type(4)));
typedef unsigned int  uintx4 __attribute__((ext_vector_type(4)));
typedef unsigned long long ulongx2 __attribute__((ext_vector_type(2)));
typedef unsigned short      ushort_t;
typedef unsigned int        uint_t;
typedef unsigned long long  ulong_t;

// workspace byte offsets (total 63,668,224 B < proven 69,861,376)
#define HT_B     0ull                 // bf16 ht[1024][16384]           = 33,554,432
#define WQ_B     33554432ull          // bf16 wq[4][18][4][4][64][8]    =  1,179,648
#define WB_B     34734080ull          // bf16 wb[1024][768]             =  1,572,864
#define SH_B     36306944ull          // xbf[16384][768] bf16 (25.2MB)  OVERLAPS kanp[4][16384][64] f32 (16.8MB)
#define KANR_B   61472768ull          // bf16 kanr[16384][64]           =  2,097,152
#define WFQ_B    63569920ull          // bf16 wfq[6][2][2][4][64][8]    =     98,304

static __device__ inline uint_t  fbits(float f){ return __builtin_bit_cast(uint_t, f); }
static __device__ inline ushort_t f2b(float f){
    uint_t u = fbits(f);
    return (ushort_t)((u + 0x7fffu + ((u >> 16) & 1u)) >> 16);
}
static __device__ inline float b2f(ushort_t h){ return __builtin_bit_cast(float, (uint_t)h << 16); }
static __device__ inline ulong_t pack4(float4 v){      // RNE
    return (ulong_t)f2b(v.x) | ((ulong_t)f2b(v.y) << 16) |
           ((ulong_t)f2b(v.z) << 32) | ((ulong_t)f2b(v.w) << 48);
}
static __device__ inline ulong_t pack4t(float4 v){     // truncation (cheap)
    uint_t d0 = (fbits(v.x) >> 16) | (fbits(v.y) & 0xffff0000u);
    uint_t d1 = (fbits(v.z) >> 16) | (fbits(v.w) & 0xffff0000u);
    return (ulong_t)d0 | ((ulong_t)d1 << 32);
}
static __device__ inline float fast_tanh(float x){
    const float e = __expf(2.0f * x);
    return 1.0f - 2.0f / (e + 1.0f);
}
static __device__ inline void gload_lds16(const void* g, void* l){
    __builtin_amdgcn_global_load_lds(
        (const __attribute__((address_space(1))) unsigned int*)g,
        (__attribute__((address_space(3))) unsigned int*)l, 16, 0, 0);
}

// ---------------------------------------------------------------------------
// pack_wq4: KAN weights, frag order, KS=4.
// wq[ks(4)][ss(18)][t(4)][ct(4)][ln(64)][j(8)]
//   ss<16 (bases):  i = ks*256 + ss*16 + t*4 + (ln>>4)
//   ss>=16 (silu):  i = ks*256 + (ss-16)*128 + t*32 + (ln>>4)*8 + j
// ---------------------------------------------------------------------------
__global__ __launch_bounds__(256) void pack_wq4(
    const float* __restrict__ base_w,
    const float* __restrict__ spline_w,
    const float* __restrict__ scaler,
    ushort_t* __restrict__ wq)
{
    const int e = blockIdx.x * 256 + threadIdx.x;   // 589824
    const int j    = e & 7;
    const int ln   = (e >> 3) & 63;
    const int ct   = (e >> 9) & 3;
    const int t    = (e >> 11) & 3;
    const int rest = e >> 13;        // 0..71
    const int ss   = rest % 18;
    const int ks   = rest / 18;
    const int o = ct * 16 + (ln & 15);
    const int g = ln >> 4;
    float v;
    if (ss < 16) {
        const int i = ks * 256 + ss * 16 + t * 4 + g;
        v = spline_w[(o * KIN_ + i) * 8 + j] * scaler[o * KIN_ + i];
    } else {
        const int i = ks * 256 + (ss - 16) * 128 + t * 32 + g * 8 + j;
        v = base_w[o * KIN_ + i];
    }
    wq[e] = f2b(v);
}

// ---------------------------------------------------------------------------
// pack_wb2: wb[1024][768] bf16 (rows 0..511 Wx, 512..1023 Wy)
// ---------------------------------------------------------------------------
__global__ __launch_bounds__(256) void pack_wb2(
    const float* __restrict__ Wx,
    const float* __restrict__ Wy,
    ushort_t* __restrict__ wb)
{
    const int e = blockIdx.x * 256 + threadIdx.x;   // 786432
    const float v = (e < 512 * TF_) ? Wx[e] : Wy[e - 512 * TF_];
    wb[e] = f2b(v);
}

// ---------------------------------------------------------------------------
// pack_wfq: Wf frag order. wfq[tb(6)][wvt(2)][s(2)][rt(4)][ln(64)][jj(8)]
//   tf = tb*128 + wvt*64 + rt*16 + (ln&15), o = s*32 + (ln>>4)*8 + jj
// ---------------------------------------------------------------------------
__global__ __launch_bounds__(256) void pack_wfq(
    const float* __restrict__ Wf, ushort_t* __restrict__ wfq)
{
    const int e = blockIdx.x * 256 + threadIdx.x;   // 49152
    const int jj  = e & 7;
    const int ln  = (e >> 3) & 63;
    const int rt  = (e >> 9) & 3;
    const int s   = (e >> 11) & 1;
    const int wvt = (e >> 12) & 1;
    const int tb  = e >> 13;         // 0..5
    const int tf = tb * 128 + wvt * 64 + rt * 16 + (ln & 15);
    const int o  = s * 32 + (ln >> 4) * 8 + jj;
    wfq[e] = f2b(Wf[(size_t)tf * 64 + o]);
}

// ---------------------------------------------------------------------------
// xcvt: xbf[m][k] bf16  <-  Xs[b][t][n][f] fp32  (k = t*8+f, m = b*512+n)
// grid (16 n-tiles, 32 b), 256 thr. LDS-mediated transpose, coalesced IO.
// ---------------------------------------------------------------------------
__global__ __launch_bounds__(256) void xcvt_kernel(
    const float* __restrict__ Xs, ushort_t* __restrict__ xbf)
{
    __shared__ __align__(16) char lds[32 * 1552];
    const int tid = threadIdx.x;
    const int n0  = blockIdx.x * 32;
    const int bb  = blockIdx.y;
    const int nl  = (tid & 63) >> 1;
    const int f4  = (tid & 1) * 4;
    const int tq  = tid >> 6;
    #pragma unroll 4
    for (int u = 0; u < 24; u++) {
        const int t = u * 4 + tq;
        const float4 v = *(const float4*)(Xs + (size_t)bb * (T_ * N_ * F_)
                                             + (size_t)t * (N_ * F_)
                                             + (size_t)(n0 + nl) * F_ + f4);
        *(ulong_t*)(lds + nl * 1552 + t * 16 + f4 * 2) = pack4t(v);
    }
    __syncthreads();
    #pragma unroll 4
    for (int u = 0; u < 12; u++) {
        const int c   = u * 256 + tid;      // 0..3071
        const int row = c / 96;
        const int col = c - row * 96;
        const uintx4 val = *(const uintx4*)(lds + row * 1552 + col * 16);
        *(uintx4*)(xbf + (size_t)(bb * 512 + n0 + row) * TF_ + col * 8) = val;
    }
}

// ---------------------------------------------------------------------------
// gemm_tanh_v7 (m97-pattern, both operands via global_load_lds):
// ht[j0+j][m] = tanh( sum_k xbf[m,k]*wb[j0+j,k] + bias[jl0+j] )
// 128x128 tile, BK=64, 512 thr (8 waves, each 64m x 32j, acc 4x2).
// LDS 32KB single-buffer (A 16K + B 16K), XOR-swizzled; 2 barriers/K-step.
// ---------------------------------------------------------------------------
__global__ __launch_bounds__(512, 2) void gemm_tanh_v7(
    const ushort_t* __restrict__ xbf,
    const ushort_t* __restrict__ wb,
    const float* __restrict__ bias,
    ushort_t* __restrict__ ht, int z)
{
    __shared__ __align__(16) char smem[32768];

    const int tid = threadIdx.x;
    const int wv  = tid >> 6;          // 0..7
    const int ln  = tid & 63;
    const int lr  = ln & 15;
    const int hi  = ln >> 4;
    const int wm  = wv >> 2;           // m-half
    const int wj  = wv & 3;            // j-quarter (32 cols)

    const int m0  = blockIdx.x * 128;
    const int jl0 = blockIdx.y * 128;
    const int j0  = z * 512 + jl0;

    const int r_l = ln >> 3;                    // row within 8-row region
    const int ck  = ((ln & 7) ^ r_l) * 8;       // inverse-swizzled src chunk

    f32x4 acc[4][2] = {};

    for (int kt = 0; kt < 12; kt++) {
        __syncthreads();
        #pragma unroll
        for (int s = 0; s < 2; s++) {
            const int reg = s * 8 + wv;          // 0..15
            const int row = reg * 8 + r_l;
            gload_lds16(xbf + (size_t)(m0 + row) * TF_ + kt * 64 + ck,
                        smem + reg * 1024 + ln * 16);
            gload_lds16(wb + (size_t)(j0 + row) * TF_ + kt * 64 + ck,
                        smem + 16384 + reg * 1024 + ln * 16);
        }
        __syncthreads();

        #pragma unroll
        for (int h = 0; h < 2; h++) {
            const int g = h * 4 + hi;
            short8 a[4], b[2];
            #pragma unroll
            for (int rt = 0; rt < 4; rt++) {
                const int r = wm * 64 + rt * 16 + lr;
                a[rt] = *(short8*)(smem + r * 128 + ((g ^ (r & 7)) * 16));
            }
            #pragma unroll
            for (int ct = 0; ct < 2; ct++) {
                const int r = wj * 32 + ct * 16 + lr;
                b[ct] = *(short8*)(smem + 16384 + r * 128 + ((g ^ (r & 7)) * 16));
            }
            #pragma unroll
            for (int rt = 0; rt < 4; rt++)
                #pragma unroll
                for (int ct = 0; ct < 2; ct++)
                    acc[rt][ct] = __builtin_amdgcn_mfma_f32_16x16x32_bf16(
                        a[rt], b[ct], acc[rt][ct], 0, 0, 0);
        }
    }

    // epilogue: tanh -> bf16 LDS [j 128][m 128] (16B-slot ^ (j&15)) -> ht
    __syncthreads();
    #pragma unroll
    for (int ct = 0; ct < 2; ct++) {
        const int j = wj * 32 + ct * 16 + lr;
        const float bvv = bias[jl0 + j];
        #pragma unroll
        for (int rt = 0; rt < 4; rt++) {
            const f32x4 v = acc[rt][ct];
            float4 tv;
            tv.x = fast_tanh(v[0] + bvv);
            tv.y = fast_tanh(v[1] + bvv);
            tv.z = fast_tanh(v[2] + bvv);
            tv.w = fast_tanh(v[3] + bvv);
            const int slot = wm * 8 + rt * 2 + (hi >> 1);
            *(ulong_t*)(smem + j * 256 + ((slot ^ (j & 15)) * 16) + (hi & 1) * 8)
                = pack4(tv);
        }
    }
    __syncthreads();
    {
        const int j  = tid >> 2;             // 0..127
        const int q4 = tid & 3;
        ushort_t* dst = ht + (size_t)(j0 + j) * M_ + m0 + q4 * 32;
        #pragma unroll
        for (int w = 0; w < 4; w++) {
            const int slot = q4 * 4 + w;
            short8 val = *(short8*)(smem + j * 256 + ((slot ^ (j & 15)) * 16));
            *(short8*)(dst + w * 8) = val;
        }
    }
}

// ---------------------------------------------------------------------------
// kan_v4: zero-LDS, KS=4, 64 rows/block (4 waves x 16 rows), grid (256,4).
// ---------------------------------------------------------------------------
static __device__ inline short8 eval_bases(float x)
{
    const float v = fmaf(x, 2.5f, 2.5f);
    float sf = floorf(v);
    sf = fminf(fmaxf(sf, 0.0f), 4.0f);
    const float u = v - sf;
    const int si = (int)sf;
    const float u2 = u * u, u3 = u2 * u;
    const float omu = 1.0f - u;
    const float omu3 = omu * omu * omu;
    const float Bb0 = omu3 * (1.0f / 6.0f);
    const float Bb3 = u3 * (1.0f / 6.0f);
    const float Bb1 = fmaf(0.5f, u3, 2.0f / 3.0f) - u2;
    const float Bb2 = 1.0f - Bb0 - Bb1 - Bb3;
    const uint_t d0 = (fbits(Bb0) >> 16) | (fbits(Bb1) & 0xffff0000u);
    const uint_t d1 = (fbits(Bb2) >> 16) | (fbits(Bb3) & 0xffff0000u);
    const ulong_t P = (ulong_t)d0 | ((ulong_t)d1 << 32);
    const int sh = si << 4;
    const ulong_t Plo = P << (sh & 63);
    const ulong_t Phi = P >> ((64 - sh) & 63);
    ulongx2 pr;
    pr.x = (si == 4) ? 0ull : Plo;
    pr.y = (si == 0) ? 0ull : ((si == 4) ? P : Phi);
    return __builtin_bit_cast(short8, pr);
}

static __device__ inline short8 eval_silu8(const ushort_t* __restrict__ ht, int ib0, size_t r)
{
    uintx4 d;
    #pragma unroll
    for (int jj = 0; jj < 4; jj++) {
        const float x0 = b2f(ht[(size_t)(ib0 + 2 * jj)     * M_ + r]);
        const float x1 = b2f(ht[(size_t)(ib0 + 2 * jj + 1) * M_ + r]);
        const float s0 = x0 / (1.0f + __expf(-x0));
        const float s1 = x1 / (1.0f + __expf(-x1));
        d[jj] = (fbits(s0) >> 16) | (fbits(s1) & 0xffff0000u);
    }
    return __builtin_bit_cast(short8, d);
}

__global__ __launch_bounds__(256) void kan_v4(
    const ushort_t* __restrict__ ht,
    const ushort_t* __restrict__ wq,
    float* __restrict__ kanp)
{
    const int tid = threadIdx.x;
    const int wv  = tid >> 6;
    const int ln  = tid & 63;
    const int g   = ln >> 4;
    const int lr  = ln & 15;
    const int m0  = blockIdx.x * 64;
    const int ks  = blockIdx.y;
    const int iB  = ks * 256;
    const size_t r0 = (size_t)(m0 + wv * 16 + lr);

    const short8* wqf = (const short8*)wq + (size_t)ks * 18432 + ln;

    f32x4 acc[4] = {};

    for (int ss = 0; ss < 16; ss++) {
        #pragma unroll
        for (int t = 0; t < 4; t++) {
            const short8* bp = wqf + (size_t)(ss * 4 + t) * 256;
            const short8 b0 = bp[0], b1 = bp[64], b2 = bp[128], b3 = bp[192];
            const int i = iB + ss * 16 + t * 4 + g;
            const short8 a0 = eval_bases(b2f(ht[(size_t)i * M_ + r0]));
            acc[0] = __builtin_amdgcn_mfma_f32_16x16x32_bf16(a0, b0, acc[0], 0, 0, 0);
            acc[1] = __builtin_amdgcn_mfma_f32_16x16x32_bf16(a0, b1, acc[1], 0, 0, 0);
            acc[2] = __builtin_amdgcn_mfma_f32_16x16x32_bf16(a0, b2, acc[2], 0, 0, 0);
            acc[3] = __builtin_amdgcn_mfma_f32_16x16x32_bf16(a0, b3, acc[3], 0, 0, 0);
        }
    }
    #pragma unroll
    for (int st = 0; st < 2; st++) {
        #pragma unroll
        for (int t = 0; t < 4; t++) {
            const short8* bp = wqf + (size_t)((16 + st) * 4 + t) * 256;
            const short8 b0 = bp[0], b1 = bp[64], b2 = bp[128], b3 = bp[192];
            const int ib0 = iB + st * 128 + t * 32 + g * 8;
            const short8 a0 = eval_silu8(ht, ib0, r0);
            acc[0] = __builtin_amdgcn_mfma_f32_16x16x32_bf16(a0, b0, acc[0], 0, 0, 0);
            acc[1] = __builtin_amdgcn_mfma_f32_16x16x32_bf16(a0, b1, acc[1], 0, 0, 0);
            acc[2] = __builtin_amdgcn_mfma_f32_16x16x32_bf16(a0, b2, acc[2], 0, 0, 0);
            acc[3] = __builtin_amdgcn_mfma_f32_16x16x32_bf16(a0, b3, acc[3], 0, 0, 0);
        }
    }

    // C layout: col = lr (o-part), row = hi*4 + q (m-part within the 16 rows)
    #pragma unroll
    for (int ct = 0; ct < 4; ct++) {
        const int o = ct * 16 + lr;
        #pragma unroll
        for (int q = 0; q < 4; q++) {
            const size_t row = (size_t)(m0 + wv * 16 + (ln >> 4) * 4 + q);
            kanp[(size_t)ks * (M_ * 64) + row * 64 + o] = acc[ct][q];
        }
    }
}

// ---------------------------------------------------------------------------
// reduce_kan: kanr[m][o] bf16 = sum_ks kanp[ks][m][o]
// ---------------------------------------------------------------------------
__global__ __launch_bounds__(256) void reduce_kan(
    const float* __restrict__ kanp, ushort_t* __restrict__ kanr)
{
    const int e8 = blockIdx.x * 256 + threadIdx.x;   // 131072 threads
    const size_t base = (size_t)e8 * 8;
    float4 s0 = *(const float4*)(kanp + base);
    float4 s1 = *(const float4*)(kanp + base + 4);
    #pragma unroll
    for (int p = 1; p < KS_; p++) {
        const float4 a0 = *(const float4*)(kanp + (size_t)p * (M_ * 64) + base);
        const float4 a1 = *(const float4*)(kanp + (size_t)p * (M_ * 64) + base + 4);
        s0.x += a0.x; s0.y += a0.y; s0.z += a0.z; s0.w += a0.w;
        s1.x += a1.x; s1.y += a1.y; s1.z += a1.z; s1.w += a1.w;
    }
    ulongx2 outv;
    outv.x = pack4(s0);
    outv.y = pack4(s1);
    *(ulongx2*)(kanr + base) = outv;
}

// ---------------------------------------------------------------------------
// final_v2 (MFMA, swapped operands -> float4 out stores):
// out[b][t][n][f] = sum_o kanr[m][o]*Wf[tf][o] + bf[tf]
// grid (128 m-blocks, 6 tf-blocks), 256 thr (4 waves: wvm x wvt).
// ---------------------------------------------------------------------------
__global__ __launch_bounds__(256) void final_v2(
    const ushort_t* __restrict__ kanr,
    const ushort_t* __restrict__ wfq,
    const float* __restrict__ bf,
    float* __restrict__ out)
{
    const int tid = threadIdx.x;
    const int wv  = tid >> 6;
    const int ln  = tid & 63;
    const int lr  = ln & 15;
    const int hi  = ln >> 4;
    const int wvm = wv >> 1;
    const int wvt = wv & 1;
    const int mb  = blockIdx.x;
    const int tb  = blockIdx.y;

    f32x4 acc[4][4] = {};

    #pragma unroll
    for (int s = 0; s < 2; s++) {
        short8 afr[4], bfr[4];
        #pragma unroll
        for (int rt = 0; rt < 4; rt++) {
            const size_t idx = ((size_t)(((tb * 2 + wvt) * 2 + s) * 4 + rt)) * 64 + ln;
            afr[rt] = ((const short8*)wfq)[idx];
        }
        #pragma unroll
        for (int ct = 0; ct < 4; ct++) {
            const int m = mb * 128 + wvm * 64 + ct * 16 + lr;
            bfr[ct] = *(const short8*)(kanr + (size_t)m * 64 + s * 32 + hi * 8);
        }
        #pragma unroll
        for (int rt = 0; rt < 4; rt++)
            #pragma unroll
            for (int ct = 0; ct < 4; ct++)
                acc[rt][ct] = __builtin_amdgcn_mfma_f32_16x16x32_bf16(
                    afr[rt], bfr[ct], acc[rt][ct], 0, 0, 0);
    }

    // C: row (tf) = rt*16 + hi*4 + q ; col (m) = ct*16 + lr
    #pragma unroll
    for (int rt = 0; rt < 4; rt++) {
        const int tf0 = tb * 128 + wvt * 64 + rt * 16 + hi * 4;
        const float4 b4 = *(const float4*)&bf[tf0];
        const int t  = tf0 >> 3;
        const int f0 = tf0 & 7;
        #pragma unroll
        for (int ct = 0; ct < 4; ct++) {
            const int m = mb * 128 + wvm * 64 + ct * 16 + lr;
            const int bb = m >> 9;
            const int n  = m & 511;
            const f32x4 v = acc[rt][ct];
            float4 o4 = make_float4(v[0] + b4.x, v[1] + b4.y, v[2] + b4.z, v[3] + b4.w);
            *(float4*)&out[(size_t)bb * (T_ * N_ * F_)
                           + (size_t)t * (N_ * F_)
                           + (size_t)n * F_ + f0] = o4;
        }
    }
}

// ---------------------------------------------------------------------------
extern "C" void kernel_launch(void* const* d_in, const int* in_sizes, int n_in,
                              void* d_out, int out_size, void* d_ws, size_t ws_size,
                              hipStream_t stream)
{
    const float* X      = (const float*)d_in[0];
    const float* Y      = (const float*)d_in[1];
    const float* Wx     = (const float*)d_in[2];
    const float* bx     = (const float*)d_in[3];
    const float* Wy     = (const float*)d_in[4];
    const float* by     = (const float*)d_in[5];
    const float* base_w = (const float*)d_in[6];
    const float* spline_w = (const float*)d_in[7];
    const float* spline_scaler = (const float*)d_in[8];
    const float* Wf     = (const float*)d_in[9];
    const float* bf     = (const float*)d_in[10];

    float* out = (float*)d_out;
    ushort_t* ht   = (ushort_t*)((char*)d_ws + HT_B);
    ushort_t* wq   = (ushort_t*)((char*)d_ws + WQ_B);
    ushort_t* wb   = (ushort_t*)((char*)d_ws + WB_B);
    ushort_t* xbf  = (ushort_t*)((char*)d_ws + SH_B);   // overlaps kanp
    float*    kanp = (float*)((char*)d_ws + SH_B);
    ushort_t* kanr = (ushort_t*)((char*)d_ws + KANR_B);
    ushort_t* wfq  = (ushort_t*)((char*)d_ws + WFQ_B);

    pack_wq4<<<2304, 256, 0, stream>>>(base_w, spline_w, spline_scaler, wq);
    pack_wb2<<<3072, 256, 0, stream>>>(Wx, Wy, wb);
    pack_wfq<<<192, 256, 0, stream>>>(Wf, wfq);

    // X half: convert then GEMM (xbf reused for Y afterwards)
    xcvt_kernel<<<dim3(16, 32), 256, 0, stream>>>(X, xbf);
    gemm_tanh_v7<<<dim3(128, 4), 512, 0, stream>>>(xbf, wb, bx, ht, 0);
    xcvt_kernel<<<dim3(16, 32), 256, 0, stream>>>(Y, xbf);
    gemm_tanh_v7<<<dim3(128, 4), 512, 0, stream>>>(xbf, wb, by, ht, 1);

    kan_v4<<<dim3(M_ / 64, KS_), 256, 0, stream>>>(ht, wq, kanp);
    reduce_kan<<<512, 256, 0, stream>>>(kanp, kanr);
    final_v2<<<dim3(128, 6), 256, 0, stream>>>(kanr, wfq, bf, out);
}

// Round 8
// 144.613 us; speedup vs baseline: 5.5571x; 1.0124x over previous
//
#include <hip/hip_runtime.h>
#include <cmath>

#define B_    32
#define T_    96
#define N_    512
#define F_    8
#define TF_   768
#define HID_  512
#define M_    16384
#define KIN_  1024
#define KS_   8        // K-split for kan

typedef short short8 __attribute__((ext_vector_type(8)));
typedef float f32x4  __attribute__((ext_vector_type(4)));
typedef unsigned int  uintx4 __attribute__((ext_vector_type(4)));
typedef unsigned long long ulongx2 __attribute__((ext_vector_type(2)));
typedef _Float16 halfx8 __attribute__((ext_vector_type(8)));
typedef unsigned short      ushort_t;
typedef unsigned int        uint_t;
typedef unsigned long long  ulong_t;

// workspace byte offsets (total 63,668,224 B — unchanged from round 7)
#define HT_B     0ull                 // bf16 ht[1024][16384]           = 33,554,432
#define WQ_B     33554432ull          // bf16 wq[8][9][4][4][64][8]     =  1,179,648
#define WB_B     34734080ull          // bf16 wb[1024][768]             =  1,572,864
#define SH_B     36306944ull          // xbf[16384][768] bf16 (25.2MB)  OVERLAPS kanp[8][16384][64] fp16 (16.8MB)
#define KANR_B   61472768ull          // bf16 kanr[16384][64]           =  2,097,152
#define WFQ_B    63569920ull          // bf16 wfq[6][2][2][4][64][8]    =     98,304

static __device__ inline uint_t  fbits(float f){ return __builtin_bit_cast(uint_t, f); }
static __device__ inline ushort_t f2b(float f){
    uint_t u = fbits(f);
    return (ushort_t)((u + 0x7fffu + ((u >> 16) & 1u)) >> 16);
}
static __device__ inline float b2f(ushort_t h){ return __builtin_bit_cast(float, (uint_t)h << 16); }
static __device__ inline ulong_t pack4(float4 v){      // RNE
    return (ulong_t)f2b(v.x) | ((ulong_t)f2b(v.y) << 16) |
           ((ulong_t)f2b(v.z) << 32) | ((ulong_t)f2b(v.w) << 48);
}
static __device__ inline ulong_t pack4t(float4 v){     // truncation (cheap)
    uint_t d0 = (fbits(v.x) >> 16) | (fbits(v.y) & 0xffff0000u);
    uint_t d1 = (fbits(v.z) >> 16) | (fbits(v.w) & 0xffff0000u);
    return (ulong_t)d0 | ((ulong_t)d1 << 32);
}
static __device__ inline float fast_tanh(float x){
    const float e = __expf(2.0f * x);
    return 1.0f - 2.0f / (e + 1.0f);
}
static __device__ inline void gload_lds16(const void* g, void* l){
    __builtin_amdgcn_global_load_lds(
        (const __attribute__((address_space(1))) unsigned int*)g,
        (__attribute__((address_space(3))) unsigned int*)l, 16, 0, 0);
}

// ---------------------------------------------------------------------------
// pack_wq: KAN weights, frag order, KS=8 (round-3 proven layout).
// wq[ks][ss][t][ct][ln][j].  ss<8: i = ks*128 + ss*16 + t*4 + (ln>>4);
// ss==8 (silu): i = ks*128 + t*32 + (ln>>4)*8 + j.
// ---------------------------------------------------------------------------
__global__ __launch_bounds__(256) void pack_wq(
    const float* __restrict__ base_w,
    const float* __restrict__ spline_w,
    const float* __restrict__ scaler,
    ushort_t* __restrict__ wq)
{
    const int e = blockIdx.x * 256 + threadIdx.x;   // 589824
    const int j    = e & 7;
    const int ln   = (e >> 3) & 63;
    const int ct   = (e >> 9) & 3;
    const int t    = (e >> 11) & 3;
    const int rest = e >> 13;        // 0..71
    const int ss   = rest % 9;
    const int ks   = rest / 9;
    const int o = ct * 16 + (ln & 15);
    const int g = ln >> 4;
    float v;
    if (ss < 8) {
        const int i = ks * 128 + ss * 16 + t * 4 + g;
        v = spline_w[(o * KIN_ + i) * 8 + j] * scaler[o * KIN_ + i];
    } else {
        const int i = ks * 128 + t * 32 + g * 8 + j;
        v = base_w[o * KIN_ + i];
    }
    wq[e] = f2b(v);
}

// ---------------------------------------------------------------------------
// pack_wb2: wb[1024][768] bf16 (rows 0..511 Wx, 512..1023 Wy)
// ---------------------------------------------------------------------------
__global__ __launch_bounds__(256) void pack_wb2(
    const float* __restrict__ Wx,
    const float* __restrict__ Wy,
    ushort_t* __restrict__ wb)
{
    const int e = blockIdx.x * 256 + threadIdx.x;   // 786432
    const float v = (e < 512 * TF_) ? Wx[e] : Wy[e - 512 * TF_];
    wb[e] = f2b(v);
}

// ---------------------------------------------------------------------------
// pack_wfq: Wf frag order (unchanged).
// ---------------------------------------------------------------------------
__global__ __launch_bounds__(256) void pack_wfq(
    const float* __restrict__ Wf, ushort_t* __restrict__ wfq)
{
    const int e = blockIdx.x * 256 + threadIdx.x;   // 49152
    const int jj  = e & 7;
    const int ln  = (e >> 3) & 63;
    const int rt  = (e >> 9) & 3;
    const int s   = (e >> 11) & 1;
    const int wvt = (e >> 12) & 1;
    const int tb  = e >> 13;         // 0..5
    const int tf = tb * 128 + wvt * 64 + rt * 16 + (ln & 15);
    const int o  = s * 32 + (ln >> 4) * 8 + jj;
    wfq[e] = f2b(Wf[(size_t)tf * 64 + o]);
}

// ---------------------------------------------------------------------------
// xcvt: xbf[m][k] bf16  <-  Xs[b][t][n][f] fp32  (unchanged)
// ---------------------------------------------------------------------------
__global__ __launch_bounds__(256) void xcvt_kernel(
    const float* __restrict__ Xs, ushort_t* __restrict__ xbf)
{
    __shared__ __align__(16) char lds[32 * 1552];
    const int tid = threadIdx.x;
    const int n0  = blockIdx.x * 32;
    const int bb  = blockIdx.y;
    const int nl  = (tid & 63) >> 1;
    const int f4  = (tid & 1) * 4;
    const int tq  = tid >> 6;
    #pragma unroll 4
    for (int u = 0; u < 24; u++) {
        const int t = u * 4 + tq;
        const float4 v = *(const float4*)(Xs + (size_t)bb * (T_ * N_ * F_)
                                             + (size_t)t * (N_ * F_)
                                             + (size_t)(n0 + nl) * F_ + f4);
        *(ulong_t*)(lds + nl * 1552 + t * 16 + f4 * 2) = pack4t(v);
    }
    __syncthreads();
    #pragma unroll 4
    for (int u = 0; u < 12; u++) {
        const int c   = u * 256 + tid;      // 0..3071
        const int row = c / 96;
        const int col = c - row * 96;
        const uintx4 val = *(const uintx4*)(lds + row * 1552 + col * 16);
        *(uintx4*)(xbf + (size_t)(bb * 512 + n0 + row) * TF_ + col * 8) = val;
    }
}

// ---------------------------------------------------------------------------
// gemm_tanh_v7 (unchanged).
// ---------------------------------------------------------------------------
__global__ __launch_bounds__(512, 2) void gemm_tanh_v7(
    const ushort_t* __restrict__ xbf,
    const ushort_t* __restrict__ wb,
    const float* __restrict__ bias,
    ushort_t* __restrict__ ht, int z)
{
    __shared__ __align__(16) char smem[32768];

    const int tid = threadIdx.x;
    const int wv  = tid >> 6;          // 0..7
    const int ln  = tid & 63;
    const int lr  = ln & 15;
    const int hi  = ln >> 4;
    const int wm  = wv >> 2;           // m-half
    const int wj  = wv & 3;            // j-quarter (32 cols)

    const int m0  = blockIdx.x * 128;
    const int jl0 = blockIdx.y * 128;
    const int j0  = z * 512 + jl0;

    const int r_l = ln >> 3;                    // row within 8-row region
    const int ck  = ((ln & 7) ^ r_l) * 8;       // inverse-swizzled src chunk

    f32x4 acc[4][2] = {};

    for (int kt = 0; kt < 12; kt++) {
        __syncthreads();
        #pragma unroll
        for (int s = 0; s < 2; s++) {
            const int reg = s * 8 + wv;          // 0..15
            const int row = reg * 8 + r_l;
            gload_lds16(xbf + (size_t)(m0 + row) * TF_ + kt * 64 + ck,
                        smem + reg * 1024 + ln * 16);
            gload_lds16(wb + (size_t)(j0 + row) * TF_ + kt * 64 + ck,
                        smem + 16384 + reg * 1024 + ln * 16);
        }
        __syncthreads();

        #pragma unroll
        for (int h = 0; h < 2; h++) {
            const int g = h * 4 + hi;
            short8 a[4], b[2];
            #pragma unroll
            for (int rt = 0; rt < 4; rt++) {
                const int r = wm * 64 + rt * 16 + lr;
                a[rt] = *(short8*)(smem + r * 128 + ((g ^ (r & 7)) * 16));
            }
            #pragma unroll
            for (int ct = 0; ct < 2; ct++) {
                const int r = wj * 32 + ct * 16 + lr;
                b[ct] = *(short8*)(smem + 16384 + r * 128 + ((g ^ (r & 7)) * 16));
            }
            #pragma unroll
            for (int rt = 0; rt < 4; rt++)
                #pragma unroll
                for (int ct = 0; ct < 2; ct++)
                    acc[rt][ct] = __builtin_amdgcn_mfma_f32_16x16x32_bf16(
                        a[rt], b[ct], acc[rt][ct], 0, 0, 0);
        }
    }

    // epilogue: tanh -> bf16 LDS [j 128][m 128] (16B-slot ^ (j&15)) -> ht
    __syncthreads();
    #pragma unroll
    for (int ct = 0; ct < 2; ct++) {
        const int j = wj * 32 + ct * 16 + lr;
        const float bvv = bias[jl0 + j];
        #pragma unroll
        for (int rt = 0; rt < 4; rt++) {
            const f32x4 v = acc[rt][ct];
            float4 tv;
            tv.x = fast_tanh(v[0] + bvv);
            tv.y = fast_tanh(v[1] + bvv);
            tv.z = fast_tanh(v[2] + bvv);
            tv.w = fast_tanh(v[3] + bvv);
            const int slot = wm * 8 + rt * 2 + (hi >> 1);
            *(ulong_t*)(smem + j * 256 + ((slot ^ (j & 15)) * 16) + (hi & 1) * 8)
                = pack4(tv);
        }
    }
    __syncthreads();
    {
        const int j  = tid >> 2;             // 0..127
        const int q4 = tid & 3;
        ushort_t* dst = ht + (size_t)(j0 + j) * M_ + m0 + q4 * 32;
        #pragma unroll
        for (int w = 0; w < 4; w++) {
            const int slot = q4 * 4 + w;
            short8 val = *(short8*)(smem + j * 256 + ((slot ^ (j & 15)) * 16));
            *(short8*)(dst + w * 8) = val;
        }
    }
}

// ---------------------------------------------------------------------------
// kan_v5: zero-LDS, KS=8, 64 rows/block (4 waves x 16 rows), grid (256,8)
// = 2048 blocks = 8 blocks/CU = 32 waves/CU.  fp16 partials.
// ---------------------------------------------------------------------------
static __device__ inline short8 eval_bases(float x)
{
    const float v = fmaf(x, 2.5f, 2.5f);
    float sf = floorf(v);
    sf = fminf(fmaxf(sf, 0.0f), 4.0f);
    const float u = v - sf;
    const int si = (int)sf;
    const float u2 = u * u, u3 = u2 * u;
    const float omu = 1.0f - u;
    const float omu3 = omu * omu * omu;
    const float Bb0 = omu3 * (1.0f / 6.0f);
    const float Bb3 = u3 * (1.0f / 6.0f);
    const float Bb1 = fmaf(0.5f, u3, 2.0f / 3.0f) - u2;
    const float Bb2 = 1.0f - Bb0 - Bb1 - Bb3;
    const uint_t d0 = (fbits(Bb0) >> 16) | (fbits(Bb1) & 0xffff0000u);
    const uint_t d1 = (fbits(Bb2) >> 16) | (fbits(Bb3) & 0xffff0000u);
    const ulong_t P = (ulong_t)d0 | ((ulong_t)d1 << 32);
    const int sh = si << 4;
    const ulong_t Plo = P << (sh & 63);
    const ulong_t Phi = P >> ((64 - sh) & 63);
    ulongx2 pr;
    pr.x = (si == 4) ? 0ull : Plo;
    pr.y = (si == 0) ? 0ull : ((si == 4) ? P : Phi);
    return __builtin_bit_cast(short8, pr);
}

__global__ __launch_bounds__(256) void kan_v5(
    const ushort_t* __restrict__ ht,
    const ushort_t* __restrict__ wq,
    _Float16* __restrict__ kanp)
{
    const int tid = threadIdx.x;
    const int wv  = tid >> 6;
    const int ln  = tid & 63;
    const int g   = ln >> 4;
    const int lr  = ln & 15;
    const int m0  = blockIdx.x * 64;
    const int ks  = blockIdx.y;
    const int iB  = ks * 128;
    const size_t r0 = (size_t)(m0 + wv * 16 + lr);

    const short8* wqf = (const short8*)wq + (size_t)ks * 9216 + ln;
    // hoisted per-lane ht bases: offsets below are compile-time multiples of M_
    const ushort_t* htg  = ht + (size_t)(iB + g) * M_ + r0;       // bases: + (ss*16+t*4)*M_
    const ushort_t* htg8 = ht + (size_t)(iB + g * 8) * M_ + r0;   // silu:  + (t*32+jj)*M_

    f32x4 acc[4] = {};

    for (int ss = 0; ss < 8; ss++) {
        #pragma unroll
        for (int t = 0; t < 4; t++) {
            const short8* bp = wqf + (size_t)(ss * 4 + t) * 256;
            const short8 b0 = bp[0], b1 = bp[64], b2 = bp[128], b3 = bp[192];
            const short8 a0 = eval_bases(b2f(htg[(size_t)(ss * 16 + t * 4) * M_]));
            acc[0] = __builtin_amdgcn_mfma_f32_16x16x32_bf16(a0, b0, acc[0], 0, 0, 0);
            acc[1] = __builtin_amdgcn_mfma_f32_16x16x32_bf16(a0, b1, acc[1], 0, 0, 0);
            acc[2] = __builtin_amdgcn_mfma_f32_16x16x32_bf16(a0, b2, acc[2], 0, 0, 0);
            acc[3] = __builtin_amdgcn_mfma_f32_16x16x32_bf16(a0, b3, acc[3], 0, 0, 0);
        }
    }
    // silu superstep
    #pragma unroll
    for (int t = 0; t < 4; t++) {
        const short8* bp = wqf + (size_t)(32 + t) * 256;
        const short8 b0 = bp[0], b1 = bp[64], b2 = bp[128], b3 = bp[192];
        uintx4 d;
        #pragma unroll
        for (int jj = 0; jj < 4; jj++) {
            const float x0 = b2f(htg8[(size_t)(t * 32 + 2 * jj)     * M_]);
            const float x1 = b2f(htg8[(size_t)(t * 32 + 2 * jj + 1) * M_]);
            const float s0 = x0 / (1.0f + __expf(-x0));
            const float s1 = x1 / (1.0f + __expf(-x1));
            d[jj] = (fbits(s0) >> 16) | (fbits(s1) & 0xffff0000u);
        }
        const short8 a0 = __builtin_bit_cast(short8, d);
        acc[0] = __builtin_amdgcn_mfma_f32_16x16x32_bf16(a0, b0, acc[0], 0, 0, 0);
        acc[1] = __builtin_amdgcn_mfma_f32_16x16x32_bf16(a0, b1, acc[1], 0, 0, 0);
        acc[2] = __builtin_amdgcn_mfma_f32_16x16x32_bf16(a0, b2, acc[2], 0, 0, 0);
        acc[3] = __builtin_amdgcn_mfma_f32_16x16x32_bf16(a0, b3, acc[3], 0, 0, 0);
    }

    // C layout: col (o) = ct*16+lr, row = g*4+q
    #pragma unroll
    for (int ct = 0; ct < 4; ct++) {
        const int o = ct * 16 + lr;
        #pragma unroll
        for (int q = 0; q < 4; q++) {
            const size_t row = (size_t)(m0 + wv * 16 + g * 4 + q);
            kanp[(size_t)ks * (M_ * 64) + row * 64 + o] = (_Float16)acc[ct][q];
        }
    }
}

// ---------------------------------------------------------------------------
// reduce_kan: kanr[m][o] bf16 = sum_ks kanp_fp16[ks][m][o]
// ---------------------------------------------------------------------------
__global__ __launch_bounds__(256) void reduce_kan(
    const _Float16* __restrict__ kanp, ushort_t* __restrict__ kanr)
{
    const int e8 = blockIdx.x * 256 + threadIdx.x;   // 131072 threads
    const size_t base = (size_t)e8 * 8;
    float s[8] = {};
    #pragma unroll
    for (int p = 0; p < KS_; p++) {
        const halfx8 v = *(const halfx8*)(kanp + (size_t)p * (M_ * 64) + base);
        #pragma unroll
        for (int j = 0; j < 8; j++) s[j] += (float)v[j];
    }
    float4 s0 = make_float4(s[0], s[1], s[2], s[3]);
    float4 s1 = make_float4(s[4], s[5], s[6], s[7]);
    ulongx2 outv;
    outv.x = pack4(s0);
    outv.y = pack4(s1);
    *(ulongx2*)(kanr + base) = outv;
}

// ---------------------------------------------------------------------------
// final_v2 (unchanged).
// ---------------------------------------------------------------------------
__global__ __launch_bounds__(256) void final_v2(
    const ushort_t* __restrict__ kanr,
    const ushort_t* __restrict__ wfq,
    const float* __restrict__ bf,
    float* __restrict__ out)
{
    const int tid = threadIdx.x;
    const int wv  = tid >> 6;
    const int ln  = tid & 63;
    const int lr  = ln & 15;
    const int hi  = ln >> 4;
    const int wvm = wv >> 1;
    const int wvt = wv & 1;
    const int mb  = blockIdx.x;
    const int tb  = blockIdx.y;

    f32x4 acc[4][4] = {};

    #pragma unroll
    for (int s = 0; s < 2; s++) {
        short8 afr[4], bfr[4];
        #pragma unroll
        for (int rt = 0; rt < 4; rt++) {
            const size_t idx = ((size_t)(((tb * 2 + wvt) * 2 + s) * 4 + rt)) * 64 + ln;
            afr[rt] = ((const short8*)wfq)[idx];
        }
        #pragma unroll
        for (int ct = 0; ct < 4; ct++) {
            const int m = mb * 128 + wvm * 64 + ct * 16 + lr;
            bfr[ct] = *(const short8*)(kanr + (size_t)m * 64 + s * 32 + hi * 8);
        }
        #pragma unroll
        for (int rt = 0; rt < 4; rt++)
            #pragma unroll
            for (int ct = 0; ct < 4; ct++)
                acc[rt][ct] = __builtin_amdgcn_mfma_f32_16x16x32_bf16(
                    afr[rt], bfr[ct], acc[rt][ct], 0, 0, 0);
    }

    #pragma unroll
    for (int rt = 0; rt < 4; rt++) {
        const int tf0 = tb * 128 + wvt * 64 + rt * 16 + hi * 4;
        const float4 b4 = *(const float4*)&bf[tf0];
        const int t  = tf0 >> 3;
        const int f0 = tf0 & 7;
        #pragma unroll
        for (int ct = 0; ct < 4; ct++) {
            const int m = mb * 128 + wvm * 64 + ct * 16 + lr;
            const int bb = m >> 9;
            const int n  = m & 511;
            const f32x4 v = acc[rt][ct];
            float4 o4 = make_float4(v[0] + b4.x, v[1] + b4.y, v[2] + b4.z, v[3] + b4.w);
            *(float4*)&out[(size_t)bb * (T_ * N_ * F_)
                           + (size_t)t * (N_ * F_)
                           + (size_t)n * F_ + f0] = o4;
        }
    }
}

// ---------------------------------------------------------------------------
extern "C" void kernel_launch(void* const* d_in, const int* in_sizes, int n_in,
                              void* d_out, int out_size, void* d_ws, size_t ws_size,
                              hipStream_t stream)
{
    const float* X      = (const float*)d_in[0];
    const float* Y      = (const float*)d_in[1];
    const float* Wx     = (const float*)d_in[2];
    const float* bx     = (const float*)d_in[3];
    const float* Wy     = (const float*)d_in[4];
    const float* by     = (const float*)d_in[5];
    const float* base_w = (const float*)d_in[6];
    const float* spline_w = (const float*)d_in[7];
    const float* spline_scaler = (const float*)d_in[8];
    const float* Wf     = (const float*)d_in[9];
    const float* bf     = (const float*)d_in[10];

    float* out = (float*)d_out;
    ushort_t* ht   = (ushort_t*)((char*)d_ws + HT_B);
    ushort_t* wq   = (ushort_t*)((char*)d_ws + WQ_B);
    ushort_t* wb   = (ushort_t*)((char*)d_ws + WB_B);
    ushort_t* xbf  = (ushort_t*)((char*)d_ws + SH_B);   // overlaps kanp
    _Float16* kanp = (_Float16*)((char*)d_ws + SH_B);
    ushort_t* kanr = (ushort_t*)((char*)d_ws + KANR_B);
    ushort_t* wfq  = (ushort_t*)((char*)d_ws + WFQ_B);

    pack_wq<<<2304, 256, 0, stream>>>(base_w, spline_w, spline_scaler, wq);
    pack_wb2<<<3072, 256, 0, stream>>>(Wx, Wy, wb);
    pack_wfq<<<192, 256, 0, stream>>>(Wf, wfq);

    // X half: convert then GEMM (xbf reused for Y afterwards)
    xcvt_kernel<<<dim3(16, 32), 256, 0, stream>>>(X, xbf);
    gemm_tanh_v7<<<dim3(128, 4), 512, 0, stream>>>(xbf, wb, bx, ht, 0);
    xcvt_kernel<<<dim3(16, 32), 256, 0, stream>>>(Y, xbf);
    gemm_tanh_v7<<<dim3(128, 4), 512, 0, stream>>>(xbf, wb, by, ht, 1);

    kan_v5<<<dim3(M_ / 64, KS_), 256, 0, stream>>>(ht, wq, kanp);
    reduce_kan<<<512, 256, 0, stream>>>(kanp, kanr);
    final_v2<<<dim3(128, 6), 256, 0, stream>>>(kanr, wfq, bf, out);
}